// Round 1
// baseline (685.575 us; speedup 1.0000x reference)
//
#include <hip/hip_runtime.h>
#include <math.h>

#define BB 8
#define HH 56
#define WWD 56
#define NN 3136
#define CC 256
#define DIMM 512
#define NHEAD 8
#define DHD 32
#define NQ 64
#define EPSF 1e-5f
#define SCALEF 0.04419417382415922f

__device__ __forceinline__ float gelu_f(float x) {
    return 0.5f * x * (1.f + erff(x * 0.70710678118654752f));
}

// ---------------------------------------------------------------------------
// GEMM: v[m, c] = sum_k x[m*512 + k] * w[c*256 + k]   (m = b*N+n, k < 256)
// 64x64 tile per 256-thread block, 4x4 register tile per thread.
// Writes v in BNC layout and NCHW layout.
// ---------------------------------------------------------------------------
__global__ __launch_bounds__(256) void gemm_v_k(
    const float* __restrict__ x, const float* __restrict__ w,
    float* __restrict__ v_bnc, float* __restrict__ v_nchw) {
    __shared__ float As[16][68];
    __shared__ float Ws[16][68];
    int m0 = blockIdx.x * 64, c0 = blockIdx.y * 64;
    int tx = threadIdx.x, ty = threadIdx.y;
    int tid = ty * 16 + tx;
    float acc[4][4] = {};
    for (int k0 = 0; k0 < 256; k0 += 16) {
#pragma unroll
        for (int l = 0; l < 4; l++) {
            int e = tid + l * 256;
            int r = e >> 4, kk = e & 15;
            As[kk][r] = x[(size_t)(m0 + r) * DIMM + k0 + kk];
            Ws[kk][r] = w[(size_t)(c0 + r) * 256 + k0 + kk];
        }
        __syncthreads();
#pragma unroll
        for (int kk = 0; kk < 16; kk++) {
            float a[4], b4[4];
#pragma unroll
            for (int i = 0; i < 4; i++) a[i] = As[kk][ty * 4 + i];
#pragma unroll
            for (int j = 0; j < 4; j++) b4[j] = Ws[kk][tx * 4 + j];
#pragma unroll
            for (int i = 0; i < 4; i++)
#pragma unroll
                for (int j = 0; j < 4; j++) acc[i][j] += a[i] * b4[j];
        }
        __syncthreads();
    }
#pragma unroll
    for (int i = 0; i < 4; i++) {
        int m = m0 + ty * 4 + i;
        int b = m / NN, n = m - b * NN;
#pragma unroll
        for (int j = 0; j < 4; j++) {
            int c = c0 + tx * 4 + j;
            float val = acc[i][j];
            v_bnc[(size_t)m * CC + c] = val;
            v_nchw[((size_t)b * CC + c) * NN + n] = val;
        }
    }
}

// ---------------------------------------------------------------------------
// Depthwise 3x3 conv (SAME, zero pad) + BN affine. NCHW in/out.
// ---------------------------------------------------------------------------
__global__ __launch_bounds__(256) void dwconv_bn_k(
    const float* __restrict__ in, const float* __restrict__ w,
    const float* __restrict__ g, const float* __restrict__ bparm,
    const float* __restrict__ m, const float* __restrict__ v,
    float* __restrict__ out) {
    int idx = blockIdx.x * 256 + threadIdx.x;  // over B*C*N
    int n = idx % NN;
    int bc = idx / NN;
    int c = bc % CC;
    int y = n / WWD, x = n - y * WWD;
    const float* ip = in + (size_t)bc * NN;
    const float* wp = w + c * 9;
    float acc = 0.f;
#pragma unroll
    for (int ky = -1; ky <= 1; ky++) {
        int iy = y + ky;
        if (iy < 0 || iy >= HH) continue;
#pragma unroll
        for (int kx = -1; kx <= 1; kx++) {
            int ix = x + kx;
            if (ix < 0 || ix >= WWD) continue;
            acc += ip[iy * WWD + ix] * wp[(ky + 1) * 3 + (kx + 1)];
        }
    }
    float s = g[c] * rsqrtf(v[c] + EPSF);
    out[idx] = acc * s + (bparm[c] - m[c] * s);
}

// 7x7 avg + max pool, stride 7, NCHW (B,C,56,56) -> (B,C,8,8) flattened 64
__global__ __launch_bounds__(256) void pool_k(
    const float* __restrict__ in, float* __restrict__ oavg, float* __restrict__ omax) {
    int idx = blockIdx.x * 256 + threadIdx.x;  // B*C*64
    int q = idx & 63;
    int bc = idx >> 6;
    int qy = q >> 3, qx = q & 7;
    const float* ip = in + (size_t)bc * NN + (qy * 7) * WWD + qx * 7;
    float s = 0.f, mx = -INFINITY;
    for (int py = 0; py < 7; py++)
        for (int px = 0; px < 7; px++) {
            float t = ip[py * WWD + px];
            s += t;
            mx = fmaxf(mx, t);
        }
    oavg[idx] = s * (1.f / 49.f);
    omax[idx] = mx;
}

__global__ __launch_bounds__(256) void gelu_k(float* __restrict__ a) {
    int idx = blockIdx.x * 256 + threadIdx.x;
    a[idx] = gelu_f(a[idx]);
}

// ---------------------------------------------------------------------------
// 1x1 conv (per-batch GEMM): out[b,co,n] = gelu(bn3(sum_ci W[co,ci]*X[b,ci,n] + bias))
// ---------------------------------------------------------------------------
__global__ __launch_bounds__(256) void conv3_k(
    const float* __restrict__ xin, const float* __restrict__ w,
    const float* __restrict__ bias, const float* __restrict__ g,
    const float* __restrict__ bparm, const float* __restrict__ m,
    const float* __restrict__ v, float* __restrict__ out) {
    int n0 = blockIdx.x * 64, co0 = blockIdx.y * 64, b = blockIdx.z;
    __shared__ float Ws[16][68];
    __shared__ float Xs[16][64];
    int tx = threadIdx.x, ty = threadIdx.y;
    int tid = ty * 16 + tx;
    float acc[4][4] = {};
    for (int k0 = 0; k0 < 256; k0 += 16) {
#pragma unroll
        for (int l = 0; l < 4; l++) {
            int e = tid + l * 256;
            int r = e >> 4, kk = e & 15;
            Ws[kk][r] = w[(size_t)(co0 + r) * 256 + k0 + kk];
            int kk2 = e >> 6, nn = e & 63;
            Xs[kk2][nn] = xin[((size_t)b * CC + k0 + kk2) * NN + n0 + nn];
        }
        __syncthreads();
#pragma unroll
        for (int kk = 0; kk < 16; kk++) {
            float a[4], x4[4];
#pragma unroll
            for (int i = 0; i < 4; i++) a[i] = Ws[kk][ty * 4 + i];
#pragma unroll
            for (int j = 0; j < 4; j++) x4[j] = Xs[kk][tx * 4 + j];
#pragma unroll
            for (int i = 0; i < 4; i++)
#pragma unroll
                for (int j = 0; j < 4; j++) acc[i][j] += a[i] * x4[j];
        }
        __syncthreads();
    }
#pragma unroll
    for (int i = 0; i < 4; i++) {
        int co = co0 + ty * 4 + i;
        float s = g[co] * rsqrtf(v[co] + EPSF);
        float sh = bparm[co] - m[co] * s;
        float bi = bias[co];
#pragma unroll
        for (int j = 0; j < 4; j++) {
            int n = n0 + tx * 4 + j;
            out[((size_t)b * CC + co) * NN + n] = gelu_f((acc[i][j] + bi) * s + sh);
        }
    }
}

// ---------------------------------------------------------------------------
// attn_small[b,h,i,j] = sum_{d<32} q1[b,h*32+d,i]k1[...,j] + q2[..]k2[..]
// one block per (b,h)
// ---------------------------------------------------------------------------
__global__ __launch_bounds__(256) void attn_qk_k(
    const float* __restrict__ q1, const float* __restrict__ q2,
    const float* __restrict__ k1, const float* __restrict__ k2,
    float* __restrict__ attn_s) {
    int b = blockIdx.x >> 3, h = blockIdx.x & 7;
    __shared__ float Qs[64][64];  // [dtot][i]
    __shared__ float Ks[64][64];
    int tid = threadIdx.x;
#pragma unroll
    for (int l = 0; l < 16; l++) {
        int e = tid + 256 * l;
        int dt = e >> 6, i = e & 63;
        int d = dt & 31;
        const float* sq = (dt < 32) ? q1 : q2;
        const float* sk = (dt < 32) ? k1 : k2;
        Qs[dt][i] = sq[((size_t)b * CC + h * 32 + d) * NQ + i];
        Ks[dt][i] = sk[((size_t)b * CC + h * 32 + d) * NQ + i];
    }
    __syncthreads();
    int i = tid & 63, jg = tid >> 6;
    float acc[16] = {};
    for (int dt = 0; dt < 64; dt++) {
        float qv = Qs[dt][i];
#pragma unroll
        for (int t = 0; t < 16; t++) acc[t] += qv * Ks[dt][jg * 16 + t];
    }
    float* outp = attn_s + (((size_t)(b * 8 + h) * 64 + i) * 64) + jg * 16;
#pragma unroll
    for (int t = 0; t < 16; t++) outp[t] = acc[t];
}

// ---------------------------------------------------------------------------
// Fused: bilinear 8x8->56x56 upsample of one attn row, *SCALE, softmax over N,
// then out[d] = sum_n P[n] * v[b,n,h*32+d].  One block per (b,h,q).
// ---------------------------------------------------------------------------
__global__ __launch_bounds__(256) void attn_k(
    const float* __restrict__ attn_s, const float* __restrict__ v_bnc,
    float* __restrict__ out_s) {
    int blk = blockIdx.x;
    int q = blk & 63, h = (blk >> 6) & 7, b = blk >> 9;
    __shared__ float asub[64];
    __shared__ float p[NN];
    __shared__ float red[256];
    __shared__ float pr[8][33];
    int tid = threadIdx.x;
    if (tid < 64) asub[tid] = attn_s[(((size_t)(b * 8 + h) * 64 + q) * 64) + tid] * SCALEF;
    __syncthreads();
    float lmax = -INFINITY;
    for (int n = tid; n < NN; n += 256) {
        int oy = n / WWD, ox = n - oy * WWD;
        float sy = (oy + 0.5f) * (1.f / 7.f) - 0.5f;
        float sx = (ox + 0.5f) * (1.f / 7.f) - 0.5f;
        int y0 = (int)floorf(sy);
        int x0 = (int)floorf(sx);
        float fy = sy - y0, fx = sx - x0;
        int y0c = max(y0, 0), y1c = min(y0 + 1, 7);
        int x0c = max(x0, 0), x1c = min(x0 + 1, 7);
        float v00 = asub[y0c * 8 + x0c], v01 = asub[y0c * 8 + x1c];
        float v10 = asub[y1c * 8 + x0c], v11 = asub[y1c * 8 + x1c];
        float val = (1.f - fy) * ((1.f - fx) * v00 + fx * v01) +
                    fy * ((1.f - fx) * v10 + fx * v11);
        p[n] = val;
        lmax = fmaxf(lmax, val);
    }
    red[tid] = lmax;
    __syncthreads();
    for (int s = 128; s > 0; s >>= 1) {
        if (tid < s) red[tid] = fmaxf(red[tid], red[tid + s]);
        __syncthreads();
    }
    float M = red[0];
    __syncthreads();
    float lsum = 0.f;
    for (int n = tid; n < NN; n += 256) {
        float e = expf(p[n] - M);
        p[n] = e;
        lsum += e;
    }
    red[tid] = lsum;
    __syncthreads();
    for (int s = 128; s > 0; s >>= 1) {
        if (tid < s) red[tid] += red[tid + s];
        __syncthreads();
    }
    float inv = 1.f / red[0];
    __syncthreads();
    int d = tid & 31, grp = tid >> 5;
    const float* vp = v_bnc + (size_t)b * NN * CC + h * 32 + d;
    float acc = 0.f;
    int nend = grp * 392 + 392;
    for (int n = grp * 392; n < nend; n++) acc += p[n] * vp[(size_t)n * CC];
    pr[grp][d] = acc;
    __syncthreads();
    if (tid < 32) {
        float s2 = 0.f;
#pragma unroll
        for (int g2 = 0; g2 < 8; g2++) s2 += pr[g2][tid];
        out_s[((size_t)b * CC + h * 32 + tid) * NQ + q] = s2 * inv;
    }
}

// bilinear upsample (B,C,8,8) -> (B,C,56,56)
__global__ __launch_bounds__(256) void upsample_k(
    const float* __restrict__ in, float* __restrict__ out) {
    int idx = blockIdx.x * 256 + threadIdx.x;  // B*C*N
    int n = idx % NN;
    int bc = idx / NN;
    int oy = n / WWD, ox = n - oy * WWD;
    float sy = (oy + 0.5f) * (1.f / 7.f) - 0.5f;
    float sx = (ox + 0.5f) * (1.f / 7.f) - 0.5f;
    int y0 = (int)floorf(sy);
    int x0 = (int)floorf(sx);
    float fy = sy - y0, fx = sx - x0;
    int y0c = max(y0, 0), y1c = min(y0 + 1, 7);
    int x0c = max(x0, 0), x1c = min(x0 + 1, 7);
    const float* ip = in + (size_t)bc * 64;
    float v00 = ip[y0c * 8 + x0c], v01 = ip[y0c * 8 + x1c];
    float v10 = ip[y1c * 8 + x0c], v11 = ip[y1c * 8 + x1c];
    out[idx] = (1.f - fy) * ((1.f - fx) * v00 + fx * v01) +
               fy * ((1.f - fx) * v10 + fx * v11);
}

// ---------------------------------------------------------------------------
// Final projection: y[b,n,co] = sum_{c<512} cat[c]*W[co,c] + bias[co]
// cat[c<256] = xh[b,c,n] (NCHW), cat[c>=256] = xl[b,c-256,n] (NCHW)
// ---------------------------------------------------------------------------
__global__ __launch_bounds__(256) void proj_k(
    const float* __restrict__ xh, const float* __restrict__ xl,
    const float* __restrict__ w, const float* __restrict__ bias,
    float* __restrict__ y) {
    int n0 = blockIdx.x * 64, co0 = blockIdx.y * 64, b = blockIdx.z;
    __shared__ float Ws[16][68];
    __shared__ float Xs[16][64];
    int tx = threadIdx.x, ty = threadIdx.y;
    int tid = ty * 16 + tx;
    float acc[4][4] = {};
    for (int k0 = 0; k0 < 512; k0 += 16) {
        const float* src = (k0 < 256) ? xh : xl;
        int kb = k0 & 255;
#pragma unroll
        for (int l = 0; l < 4; l++) {
            int e = tid + l * 256;
            int r = e >> 4, kk = e & 15;
            Ws[kk][r] = w[(size_t)(co0 + r) * DIMM + k0 + kk];
            int kk2 = e >> 6, nn = e & 63;
            Xs[kk2][nn] = src[((size_t)b * CC + kb + kk2) * NN + n0 + nn];
        }
        __syncthreads();
#pragma unroll
        for (int kk = 0; kk < 16; kk++) {
            float wv[4], xv[4];
#pragma unroll
            for (int j = 0; j < 4; j++) wv[j] = Ws[kk][tx * 4 + j];
#pragma unroll
            for (int i = 0; i < 4; i++) xv[i] = Xs[kk][ty * 4 + i];
#pragma unroll
            for (int i = 0; i < 4; i++)
#pragma unroll
                for (int j = 0; j < 4; j++) acc[i][j] += xv[i] * wv[j];
        }
        __syncthreads();
    }
#pragma unroll
    for (int i = 0; i < 4; i++) {
        int n = n0 + ty * 4 + i;
        float* yp = y + ((size_t)b * NN + n) * DIMM + co0 + tx * 4;
#pragma unroll
        for (int j = 0; j < 4; j++) yp[j] = acc[i][j] + bias[co0 + tx * 4 + j];
    }
}

extern "C" void kernel_launch(void* const* d_in, const int* in_sizes, int n_in,
                              void* d_out, int out_size, void* d_ws, size_t ws_size,
                              hipStream_t stream) {
    const float* x        = (const float*)d_in[0];
    const float* proj_v_w = (const float*)d_in[1];
    const float* conv1_w  = (const float*)d_in[2];
    const float* conv2_w  = (const float*)d_in[3];
    const float* conv3_w  = (const float*)d_in[4];
    const float* conv3_b  = (const float*)d_in[5];
    const float* v_conv_w = (const float*)d_in[6];
    const float* proj_w   = (const float*)d_in[7];
    const float* proj_b   = (const float*)d_in[8];
    const float* bn1_g = (const float*)d_in[9],  *bn1_b = (const float*)d_in[10];
    const float* bn1_m = (const float*)d_in[11], *bn1_v = (const float*)d_in[12];
    const float* bn2_g = (const float*)d_in[13], *bn2_b = (const float*)d_in[14];
    const float* bn2_m = (const float*)d_in[15], *bn2_v = (const float*)d_in[16];
    const float* bn3_g = (const float*)d_in[17], *bn3_b = (const float*)d_in[18];
    const float* bn3_m = (const float*)d_in[19], *bn3_v = (const float*)d_in[20];
    const float* vbn_g = (const float*)d_in[21], *vbn_b = (const float*)d_in[22];
    const float* vbn_m = (const float*)d_in[23], *vbn_v = (const float*)d_in[24];

    float* ws = (float*)d_ws;
    const size_t big = (size_t)BB * CC * NN;  // 6,422,528 floats
    float* v_bnc  = ws;            // v in (B,N,C)
    float* v_nchw = ws + big;      // v in (B,C,N); later reused as x_low
    float* bufA   = ws + 2 * big;  // xh1, later xh3 (x_high)
    float* bufB   = ws + 3 * big;  // xh2, later out_up
    float* q1 = ws + 4 * big;
    float* q2 = q1 + (size_t)BB * CC * NQ;
    float* k1 = q2 + (size_t)BB * CC * NQ;
    float* k2 = k1 + (size_t)BB * CC * NQ;
    float* attn_s = k2 + (size_t)BB * CC * NQ;            // (B,NH,64,64)
    float* out_s  = attn_s + (size_t)BB * NHEAD * NQ * NQ;  // (B,C,64)

    dim3 blk16(16, 16);
    const int NE = BB * CC * NN / 256;  // 25088 blocks for elementwise/NCHW kernels

    gemm_v_k<<<dim3(392, 4), blk16, 0, stream>>>(x, proj_v_w, v_bnc, v_nchw);
    dwconv_bn_k<<<NE, 256, 0, stream>>>(v_nchw, conv1_w, bn1_g, bn1_b, bn1_m, bn1_v, bufA);
    pool_k<<<512, 256, 0, stream>>>(bufA, q1, q2);
    gelu_k<<<NE, 256, 0, stream>>>(bufA);
    dwconv_bn_k<<<NE, 256, 0, stream>>>(bufA, conv2_w, bn2_g, bn2_b, bn2_m, bn2_v, bufB);
    pool_k<<<512, 256, 0, stream>>>(bufB, k1, k2);
    conv3_k<<<dim3(49, 4, BB), blk16, 0, stream>>>(bufB, conv3_w, conv3_b,
                                                   bn3_g, bn3_b, bn3_m, bn3_v, bufA);
    attn_qk_k<<<64, 256, 0, stream>>>(q1, q2, k1, k2, attn_s);
    attn_k<<<4096, 256, 0, stream>>>(attn_s, v_bnc, out_s);
    upsample_k<<<NE, 256, 0, stream>>>(out_s, bufB);
    dwconv_bn_k<<<NE, 256, 0, stream>>>(bufB, v_conv_w, vbn_g, vbn_b, vbn_m, vbn_v, v_nchw);
    proj_k<<<dim3(49, 8, BB), blk16, 0, stream>>>(bufA, v_nchw, proj_w, proj_b, (float*)d_out);
}

// Round 2
// 475.887 us; speedup vs baseline: 1.4406x; 1.4406x over previous
//
#include <hip/hip_runtime.h>
#include <math.h>

#define BB 8
#define HH 56
#define WWD 56
#define NN 3136
#define CC 256
#define DIMM 512
#define NHEAD 8
#define NQ 64
#define EPSF 1e-5f
#define SCALEF 0.04419417382415922f

typedef __attribute__((ext_vector_type(8))) short short8;
typedef __attribute__((ext_vector_type(4))) float floatx4;

__device__ __forceinline__ float gelu_f(float x) {
    return 0.5f * x * (1.f + erff(x * 0.70710678118654752f));
}
__device__ __forceinline__ unsigned short f2bf(float f) {
    union { float f; unsigned u; } v; v.f = f;
    return (unsigned short)((v.u + 0x7fffu + ((v.u >> 16) & 1u)) >> 16);
}

__global__ __launch_bounds__(256) void cast_k(const float* __restrict__ s,
                                              unsigned short* __restrict__ d, int n) {
    int i = blockIdx.x * 256 + threadIdx.x;
    if (i < n) d[i] = f2bf(s[i]);
}

// ===========================================================================
// MFMA GEMM: v[m, c] = sum_{k<256} x[m*512 + k] * w16[c*256 + k]
// Block tile 128m x 64c, BK=64. Writes v_bnc (B,N,C) and v_nchw (B,C,N), fp32.
// ===========================================================================
__global__ __launch_bounds__(256) void gemm_v_mfma(
    const float* __restrict__ x, const unsigned short* __restrict__ w16,
    float* __restrict__ v_bnc, float* __restrict__ v_nchw) {
    __shared__ short As[128 * 72];
    __shared__ short Bs[64 * 72];
    int m0 = blockIdx.x * 128, c0 = blockIdx.y * 64;
    int tid = threadIdx.x;
    int lane = tid & 63, wv = tid >> 6;
    int quad = lane >> 4, l16 = lane & 15;
    floatx4 zero = {0.f, 0.f, 0.f, 0.f};
    floatx4 acc[2][4];
#pragma unroll
    for (int mi = 0; mi < 2; mi++)
#pragma unroll
        for (int ci = 0; ci < 4; ci++) acc[mi][ci] = zero;

    for (int k0 = 0; k0 < 256; k0 += 64) {
        // A: x fp32, k-contiguous. thread -> (m = tid>>1, 4 octets)
        {
            int m = tid >> 1;
            int ob = (tid & 1) * 4;
            const float* src = x + (size_t)(m0 + m) * DIMM + k0 + ob * 8;
            short* dst = &As[m * 72 + ob * 8];
#pragma unroll
            for (int i2 = 0; i2 < 4; i2++) {
                floatx4 f0 = *(const floatx4*)(src + i2 * 8);
                floatx4 f1 = *(const floatx4*)(src + i2 * 8 + 4);
                short8 pk;
                pk[0] = (short)f2bf(f0[0]); pk[1] = (short)f2bf(f0[1]);
                pk[2] = (short)f2bf(f0[2]); pk[3] = (short)f2bf(f0[3]);
                pk[4] = (short)f2bf(f1[0]); pk[5] = (short)f2bf(f1[1]);
                pk[6] = (short)f2bf(f1[2]); pk[7] = (short)f2bf(f1[3]);
                *(short8*)(dst + i2 * 8) = pk;
            }
        }
        // B: w16 bf16 [c][256], direct 16B copies
#pragma unroll
        for (int i2 = 0; i2 < 2; i2++) {
            int idx = tid + 256 * i2;
            int c = idx >> 3, o = idx & 7;
            *(short8*)&Bs[c * 72 + o * 8] =
                *(const short8*)(const short*)(w16 + (size_t)(c0 + c) * 256 + k0 + o * 8);
        }
        __syncthreads();
#pragma unroll
        for (int kc = 0; kc < 2; kc++) {
            short8 af[2], bf[4];
#pragma unroll
            for (int mi = 0; mi < 2; mi++)
                af[mi] = *(const short8*)&As[(wv * 32 + mi * 16 + l16) * 72 + (kc * 4 + quad) * 8];
#pragma unroll
            for (int ci = 0; ci < 4; ci++)
                bf[ci] = *(const short8*)&Bs[(ci * 16 + l16) * 72 + (kc * 4 + quad) * 8];
#pragma unroll
            for (int mi = 0; mi < 2; mi++)
#pragma unroll
                for (int ci = 0; ci < 4; ci++)
                    acc[mi][ci] = __builtin_amdgcn_mfma_f32_16x16x32_bf16(
                        af[mi], bf[ci], acc[mi][ci], 0, 0, 0);
        }
        __syncthreads();
    }
#pragma unroll
    for (int mi = 0; mi < 2; mi++) {
        int mbase = m0 + wv * 32 + mi * 16 + quad * 4;
#pragma unroll
        for (int ci = 0; ci < 4; ci++) {
            int c = c0 + ci * 16 + l16;
#pragma unroll
            for (int r = 0; r < 4; r++) {
                int m = mbase + r;
                int b = m / NN, n = m - b * NN;
                float val = acc[mi][ci][r];
                v_bnc[(size_t)m * CC + c] = val;
                v_nchw[((size_t)b * CC + c) * NN + n] = val;
            }
        }
    }
}

// ===========================================================================
// conv3 as MFMA GEMM: xh16[m, co] = bf16(gelu(bn3((W@X)[co,m] + bias)))
// A = X (NCHW fp32, transpose-pack staging), B = conv3_w bf16. K=256.
// ===========================================================================
__global__ __launch_bounds__(256) void conv3_mfma(
    const float* __restrict__ xin, const unsigned short* __restrict__ w16,
    const float* __restrict__ bias, const float* __restrict__ g,
    const float* __restrict__ bparm, const float* __restrict__ mm,
    const float* __restrict__ vvv, unsigned short* __restrict__ out16) {
    __shared__ short As[128 * 72];
    __shared__ short Bs[64 * 72];
    int m0 = blockIdx.x * 128, c0 = blockIdx.y * 64;
    int tid = threadIdx.x;
    int lane = tid & 63, wv = tid >> 6;
    int quad = lane >> 4, l16 = lane & 15;
    int ms = tid & 127;
    int mg = m0 + ms;
    int bb = mg / NN, nn = mg - bb * NN;
    const float* arow = xin + (size_t)bb * CC * NN + nn;
    int obase = (tid >> 7) * 4;
    floatx4 zero = {0.f, 0.f, 0.f, 0.f};
    floatx4 acc[2][4];
#pragma unroll
    for (int mi = 0; mi < 2; mi++)
#pragma unroll
        for (int ci = 0; ci < 4; ci++) acc[mi][ci] = zero;

    for (int k0 = 0; k0 < 256; k0 += 64) {
#pragma unroll
        for (int ii = 0; ii < 4; ii++) {
            int o = obase + ii;
            const float* src = arow + (size_t)(k0 + o * 8) * NN;
            short8 pk;
#pragma unroll
            for (int j = 0; j < 8; j++) pk[j] = (short)f2bf(src[(size_t)j * NN]);
            *(short8*)&As[ms * 72 + o * 8] = pk;
        }
#pragma unroll
        for (int i2 = 0; i2 < 2; i2++) {
            int idx = tid + 256 * i2;
            int c = idx >> 3, o = idx & 7;
            *(short8*)&Bs[c * 72 + o * 8] =
                *(const short8*)(const short*)(w16 + (size_t)(c0 + c) * CC + k0 + o * 8);
        }
        __syncthreads();
#pragma unroll
        for (int kc = 0; kc < 2; kc++) {
            short8 af[2], bf[4];
#pragma unroll
            for (int mi = 0; mi < 2; mi++)
                af[mi] = *(const short8*)&As[(wv * 32 + mi * 16 + l16) * 72 + (kc * 4 + quad) * 8];
#pragma unroll
            for (int ci = 0; ci < 4; ci++)
                bf[ci] = *(const short8*)&Bs[(ci * 16 + l16) * 72 + (kc * 4 + quad) * 8];
#pragma unroll
            for (int mi = 0; mi < 2; mi++)
#pragma unroll
                for (int ci = 0; ci < 4; ci++)
                    acc[mi][ci] = __builtin_amdgcn_mfma_f32_16x16x32_bf16(
                        af[mi], bf[ci], acc[mi][ci], 0, 0, 0);
        }
        __syncthreads();
    }
#pragma unroll
    for (int ci = 0; ci < 4; ci++) {
        int co = c0 + ci * 16 + l16;
        float s = g[co] * rsqrtf(vvv[co] + EPSF);
        float sh = bparm[co] - mm[co] * s;
        float bi = bias[co];
#pragma unroll
        for (int mi = 0; mi < 2; mi++) {
            int mbase = m0 + wv * 32 + mi * 16 + quad * 4;
#pragma unroll
            for (int r = 0; r < 4; r++) {
                float val = gelu_f((acc[mi][ci][r] + bi) * s + sh);
                out16[(size_t)(mbase + r) * CC + co] = f2bf(val);
            }
        }
    }
}

// ===========================================================================
// Final projection MFMA: y[m, co] = sum_{k<512} cat[m,k]*W[co,k] + bias[co]
// k<256: xh16 bf16 [m][k] (direct); k>=256: xl fp32 NCHW (transpose-pack).
// ===========================================================================
__global__ __launch_bounds__(256) void proj_mfma(
    const unsigned short* __restrict__ xh16, const float* __restrict__ xl,
    const unsigned short* __restrict__ w16, const float* __restrict__ bias,
    float* __restrict__ y) {
    __shared__ short As[128 * 72];
    __shared__ short Bs[64 * 72];
    int m0 = blockIdx.x * 128, c0 = blockIdx.y * 64;
    int tid = threadIdx.x;
    int lane = tid & 63, wv = tid >> 6;
    int quad = lane >> 4, l16 = lane & 15;
    int ms = tid & 127;
    int mg = m0 + ms;
    int bb = mg / NN, nn = mg - bb * NN;
    const float* lrow = xl + (size_t)bb * CC * NN + nn;
    int obase = (tid >> 7) * 4;
    floatx4 zero = {0.f, 0.f, 0.f, 0.f};
    floatx4 acc[2][4];
#pragma unroll
    for (int mi = 0; mi < 2; mi++)
#pragma unroll
        for (int ci = 0; ci < 4; ci++) acc[mi][ci] = zero;

    for (int k0 = 0; k0 < 512; k0 += 64) {
        if (k0 < 256) {
#pragma unroll
            for (int i2 = 0; i2 < 4; i2++) {
                int idx = tid + 256 * i2;
                int m = idx >> 3, o = idx & 7;
                *(short8*)&As[m * 72 + o * 8] =
                    *(const short8*)(const short*)(xh16 + (size_t)(m0 + m) * CC + k0 + o * 8);
            }
        } else {
#pragma unroll
            for (int ii = 0; ii < 4; ii++) {
                int o = obase + ii;
                const float* src = lrow + (size_t)(k0 - 256 + o * 8) * NN;
                short8 pk;
#pragma unroll
                for (int j = 0; j < 8; j++) pk[j] = (short)f2bf(src[(size_t)j * NN]);
                *(short8*)&As[ms * 72 + o * 8] = pk;
            }
        }
#pragma unroll
        for (int i2 = 0; i2 < 2; i2++) {
            int idx = tid + 256 * i2;
            int c = idx >> 3, o = idx & 7;
            *(short8*)&Bs[c * 72 + o * 8] =
                *(const short8*)(const short*)(w16 + (size_t)(c0 + c) * DIMM + k0 + o * 8);
        }
        __syncthreads();
#pragma unroll
        for (int kc = 0; kc < 2; kc++) {
            short8 af[2], bf[4];
#pragma unroll
            for (int mi = 0; mi < 2; mi++)
                af[mi] = *(const short8*)&As[(wv * 32 + mi * 16 + l16) * 72 + (kc * 4 + quad) * 8];
#pragma unroll
            for (int ci = 0; ci < 4; ci++)
                bf[ci] = *(const short8*)&Bs[(ci * 16 + l16) * 72 + (kc * 4 + quad) * 8];
#pragma unroll
            for (int mi = 0; mi < 2; mi++)
#pragma unroll
                for (int ci = 0; ci < 4; ci++)
                    acc[mi][ci] = __builtin_amdgcn_mfma_f32_16x16x32_bf16(
                        af[mi], bf[ci], acc[mi][ci], 0, 0, 0);
        }
        __syncthreads();
    }
#pragma unroll
    for (int mi = 0; mi < 2; mi++) {
        int mbase = m0 + wv * 32 + mi * 16 + quad * 4;
#pragma unroll
        for (int ci = 0; ci < 4; ci++) {
            int co = c0 + ci * 16 + l16;
            float bi = bias[co];
#pragma unroll
            for (int r = 0; r < 4; r++)
                y[(size_t)(mbase + r) * DIMM + co] = acc[mi][ci][r] + bi;
        }
    }
}

// ---------------------------------------------------------------------------
// Depthwise 3x3 conv (SAME) + BN affine. NCHW fp32 in/out.
// ---------------------------------------------------------------------------
__global__ __launch_bounds__(256) void dwconv_bn_k(
    const float* __restrict__ in, const float* __restrict__ w,
    const float* __restrict__ g, const float* __restrict__ bparm,
    const float* __restrict__ m, const float* __restrict__ v,
    float* __restrict__ out) {
    int idx = blockIdx.x * 256 + threadIdx.x;
    int n = idx % NN;
    int bc = idx / NN;
    int c = bc % CC;
    int y = n / WWD, x = n - y * WWD;
    const float* ip = in + (size_t)bc * NN;
    const float* wp = w + c * 9;
    float acc = 0.f;
#pragma unroll
    for (int ky = -1; ky <= 1; ky++) {
        int iy = y + ky;
        if (iy < 0 || iy >= HH) continue;
#pragma unroll
        for (int kx = -1; kx <= 1; kx++) {
            int ix = x + kx;
            if (ix < 0 || ix >= WWD) continue;
            acc += ip[iy * WWD + ix] * wp[(ky + 1) * 3 + (kx + 1)];
        }
    }
    float s = g[c] * rsqrtf(v[c] + EPSF);
    out[idx] = acc * s + (bparm[c] - m[c] * s);
}

__global__ __launch_bounds__(256) void pool_k(
    const float* __restrict__ in, float* __restrict__ oavg, float* __restrict__ omax) {
    int idx = blockIdx.x * 256 + threadIdx.x;
    int q = idx & 63;
    int bc = idx >> 6;
    int qy = q >> 3, qx = q & 7;
    const float* ip = in + (size_t)bc * NN + (qy * 7) * WWD + qx * 7;
    float s = 0.f, mx = -INFINITY;
    for (int py = 0; py < 7; py++)
        for (int px = 0; px < 7; px++) {
            float t = ip[py * WWD + px];
            s += t;
            mx = fmaxf(mx, t);
        }
    oavg[idx] = s * (1.f / 49.f);
    omax[idx] = mx;
}

__global__ __launch_bounds__(256) void gelu_k(float* __restrict__ a) {
    int idx = blockIdx.x * 256 + threadIdx.x;
    a[idx] = gelu_f(a[idx]);
}

__global__ __launch_bounds__(256) void attn_qk_k(
    const float* __restrict__ q1, const float* __restrict__ q2,
    const float* __restrict__ k1, const float* __restrict__ k2,
    float* __restrict__ attn_s) {
    int b = blockIdx.x >> 3, h = blockIdx.x & 7;
    __shared__ float Qs[64][64];
    __shared__ float Ks[64][64];
    int tid = threadIdx.x;
#pragma unroll
    for (int l = 0; l < 16; l++) {
        int e = tid + 256 * l;
        int dt = e >> 6, i = e & 63;
        int d = dt & 31;
        const float* sq = (dt < 32) ? q1 : q2;
        const float* sk = (dt < 32) ? k1 : k2;
        Qs[dt][i] = sq[((size_t)b * CC + h * 32 + d) * NQ + i];
        Ks[dt][i] = sk[((size_t)b * CC + h * 32 + d) * NQ + i];
    }
    __syncthreads();
    int i = tid & 63, jg = tid >> 6;
    float acc[16] = {};
    for (int dt = 0; dt < 64; dt++) {
        float qv = Qs[dt][i];
#pragma unroll
        for (int t = 0; t < 16; t++) acc[t] += qv * Ks[dt][jg * 16 + t];
    }
    float* outp = attn_s + (((size_t)(b * 8 + h) * 64 + i) * 64) + jg * 16;
#pragma unroll
    for (int t = 0; t < 16; t++) outp[t] = acc[t];
}

__global__ __launch_bounds__(256) void attn_k(
    const float* __restrict__ attn_s, const float* __restrict__ v_bnc,
    float* __restrict__ out_s) {
    int blk = blockIdx.x;
    int q = blk & 63, h = (blk >> 6) & 7, b = blk >> 9;
    __shared__ float asub[64];
    __shared__ float p[NN];
    __shared__ float red[256];
    __shared__ float pr[8][33];
    int tid = threadIdx.x;
    if (tid < 64) asub[tid] = attn_s[(((size_t)(b * 8 + h) * 64 + q) * 64) + tid] * SCALEF;
    __syncthreads();
    float lmax = -INFINITY;
    for (int n = tid; n < NN; n += 256) {
        int oy = n / WWD, ox = n - oy * WWD;
        float sy = (oy + 0.5f) * (1.f / 7.f) - 0.5f;
        float sx = (ox + 0.5f) * (1.f / 7.f) - 0.5f;
        int y0 = (int)floorf(sy);
        int x0 = (int)floorf(sx);
        float fy = sy - y0, fx = sx - x0;
        int y0c = max(y0, 0), y1c = min(y0 + 1, 7);
        int x0c = max(x0, 0), x1c = min(x0 + 1, 7);
        float v00 = asub[y0c * 8 + x0c], v01 = asub[y0c * 8 + x1c];
        float v10 = asub[y1c * 8 + x0c], v11 = asub[y1c * 8 + x1c];
        float val = (1.f - fy) * ((1.f - fx) * v00 + fx * v01) +
                    fy * ((1.f - fx) * v10 + fx * v11);
        p[n] = val;
        lmax = fmaxf(lmax, val);
    }
    red[tid] = lmax;
    __syncthreads();
    for (int s = 128; s > 0; s >>= 1) {
        if (tid < s) red[tid] = fmaxf(red[tid], red[tid + s]);
        __syncthreads();
    }
    float M = red[0];
    __syncthreads();
    float lsum = 0.f;
    for (int n = tid; n < NN; n += 256) {
        float e = expf(p[n] - M);
        p[n] = e;
        lsum += e;
    }
    red[tid] = lsum;
    __syncthreads();
    for (int s = 128; s > 0; s >>= 1) {
        if (tid < s) red[tid] += red[tid + s];
        __syncthreads();
    }
    float inv = 1.f / red[0];
    __syncthreads();
    int d = tid & 31, grp = tid >> 5;
    const float* vp = v_bnc + (size_t)b * NN * CC + h * 32 + d;
    float acc = 0.f;
    int nend = grp * 392 + 392;
    for (int n = grp * 392; n < nend; n++) acc += p[n] * vp[(size_t)n * CC];
    pr[grp][d] = acc;
    __syncthreads();
    if (tid < 32) {
        float s2 = 0.f;
#pragma unroll
        for (int g2 = 0; g2 < 8; g2++) s2 += pr[g2][tid];
        out_s[((size_t)b * CC + h * 32 + tid) * NQ + q] = s2 * inv;
    }
}

__global__ __launch_bounds__(256) void upsample_k(
    const float* __restrict__ in, float* __restrict__ out) {
    int idx = blockIdx.x * 256 + threadIdx.x;
    int n = idx % NN;
    int bc = idx / NN;
    int oy = n / WWD, ox = n - oy * WWD;
    float sy = (oy + 0.5f) * (1.f / 7.f) - 0.5f;
    float sx = (ox + 0.5f) * (1.f / 7.f) - 0.5f;
    int y0 = (int)floorf(sy);
    int x0 = (int)floorf(sx);
    float fy = sy - y0, fx = sx - x0;
    int y0c = max(y0, 0), y1c = min(y0 + 1, 7);
    int x0c = max(x0, 0), x1c = min(x0 + 1, 7);
    const float* ip = in + (size_t)bc * 64;
    float v00 = ip[y0c * 8 + x0c], v01 = ip[y0c * 8 + x1c];
    float v10 = ip[y1c * 8 + x0c], v11 = ip[y1c * 8 + x1c];
    out[idx] = (1.f - fy) * ((1.f - fx) * v00 + fx * v01) +
               fy * ((1.f - fx) * v10 + fx * v11);
}

extern "C" void kernel_launch(void* const* d_in, const int* in_sizes, int n_in,
                              void* d_out, int out_size, void* d_ws, size_t ws_size,
                              hipStream_t stream) {
    const float* x        = (const float*)d_in[0];
    const float* proj_v_w = (const float*)d_in[1];
    const float* conv1_w  = (const float*)d_in[2];
    const float* conv2_w  = (const float*)d_in[3];
    const float* conv3_w  = (const float*)d_in[4];
    const float* conv3_b  = (const float*)d_in[5];
    const float* v_conv_w = (const float*)d_in[6];
    const float* proj_w   = (const float*)d_in[7];
    const float* proj_b   = (const float*)d_in[8];
    const float* bn1_g = (const float*)d_in[9],  *bn1_b = (const float*)d_in[10];
    const float* bn1_m = (const float*)d_in[11], *bn1_v = (const float*)d_in[12];
    const float* bn2_g = (const float*)d_in[13], *bn2_b = (const float*)d_in[14];
    const float* bn2_m = (const float*)d_in[15], *bn2_v = (const float*)d_in[16];
    const float* bn3_g = (const float*)d_in[17], *bn3_b = (const float*)d_in[18];
    const float* bn3_m = (const float*)d_in[19], *bn3_v = (const float*)d_in[20];
    const float* vbn_g = (const float*)d_in[21], *vbn_b = (const float*)d_in[22];
    const float* vbn_m = (const float*)d_in[23], *vbn_v = (const float*)d_in[24];

    float* ws = (float*)d_ws;
    const size_t big = (size_t)BB * CC * NN;  // 6,422,528 floats
    float* v_bnc  = ws;            // v (B,N,C) fp32
    float* v_nchw = ws + big;      // v (B,C,N) fp32; overlaid by xh16 after conv1
    float* bufA   = ws + 2 * big;  // xh1; later x_low (fp32 NCHW)
    float* bufB   = ws + 3 * big;  // xh2; later upsampled out
    float* q1 = ws + 4 * big;
    float* q2 = q1 + (size_t)BB * CC * NQ;
    float* k1 = q2 + (size_t)BB * CC * NQ;
    float* k2 = k1 + (size_t)BB * CC * NQ;
    float* attn_s = k2 + (size_t)BB * CC * NQ;              // (B,NH,64,64)
    float* out_s  = attn_s + (size_t)BB * NHEAD * NQ * NQ;  // (B,C,64)
    unsigned short* w16v  = (unsigned short*)(out_s + (size_t)BB * CC * NQ);
    unsigned short* w16c3 = w16v + 65536;
    unsigned short* w16p  = w16c3 + 65536;  // 262144 shorts
    unsigned short* xh16  = (unsigned short*)v_nchw;  // x_high bf16 (B,N,C); safe after conv1

    const int NE = BB * CC * NN / 256;

    cast_k<<<256, 256, 0, stream>>>(proj_v_w, w16v, 65536);
    cast_k<<<256, 256, 0, stream>>>(conv3_w, w16c3, 65536);
    cast_k<<<1024, 256, 0, stream>>>(proj_w, w16p, 262144);

    gemm_v_mfma<<<dim3(196, 4), 256, 0, stream>>>(x, w16v, v_bnc, v_nchw);
    dwconv_bn_k<<<NE, 256, 0, stream>>>(v_nchw, conv1_w, bn1_g, bn1_b, bn1_m, bn1_v, bufA);
    pool_k<<<512, 256, 0, stream>>>(bufA, q1, q2);
    gelu_k<<<NE, 256, 0, stream>>>(bufA);
    dwconv_bn_k<<<NE, 256, 0, stream>>>(bufA, conv2_w, bn2_g, bn2_b, bn2_m, bn2_v, bufB);
    pool_k<<<512, 256, 0, stream>>>(bufB, k1, k2);
    conv3_mfma<<<dim3(196, 4), 256, 0, stream>>>(bufB, w16c3, conv3_b,
                                                 bn3_g, bn3_b, bn3_m, bn3_v, xh16);
    attn_qk_k<<<64, 256, 0, stream>>>(q1, q2, k1, k2, attn_s);
    attn_k<<<4096, 256, 0, stream>>>(attn_s, v_bnc, out_s);
    upsample_k<<<NE, 256, 0, stream>>>(out_s, bufB);
    dwconv_bn_k<<<NE, 256, 0, stream>>>(bufB, v_conv_w, vbn_g, vbn_b, vbn_m, vbn_v, bufA);
    proj_mfma<<<dim3(196, 8), 256, 0, stream>>>(xh16, bufA, w16p, proj_b, (float*)d_out);
}

// Round 3
// 340.629 us; speedup vs baseline: 2.0127x; 1.3971x over previous
//
#include <hip/hip_runtime.h>
#include <math.h>

#define BB 8
#define HH 56
#define WWD 56
#define NN 3136
#define CC 256
#define DIMM 512
#define NHEAD 8
#define NQ 64
#define EPSF 1e-5f
#define SCALEF 0.04419417382415922f

typedef __attribute__((ext_vector_type(8))) short short8;
typedef __attribute__((ext_vector_type(4))) float floatx4;

__device__ __forceinline__ float gelu_f(float x) {
    return 0.5f * x * (1.f + erff(x * 0.70710678118654752f));
}
__device__ __forceinline__ unsigned short f2bf(float f) {
    union { float f; unsigned u; } v; v.f = f;
    return (unsigned short)((v.u + 0x7fffu + ((v.u >> 16) & 1u)) >> 16);
}

__global__ __launch_bounds__(256) void cast_k(const float* __restrict__ s,
                                              unsigned short* __restrict__ d, int n) {
    int i = blockIdx.x * 256 + threadIdx.x;
    if (i < n) d[i] = f2bf(s[i]);
}

// ===========================================================================
// MFMA GEMM: v[m, c] = sum_{k<256} x[m*512 + k] * w16[c*256 + k]
// Writes v_nchw fp32 (conv1 input) and v16 bf16 NCHW (attention V).
// ===========================================================================
__global__ __launch_bounds__(256) void gemm_v_mfma(
    const float* __restrict__ x, const unsigned short* __restrict__ w16,
    float* __restrict__ v_nchw, unsigned short* __restrict__ v16) {
    __shared__ short As[128 * 72];
    __shared__ short Bs[64 * 72];
    int m0 = blockIdx.x * 128, c0 = blockIdx.y * 64;
    int tid = threadIdx.x;
    int lane = tid & 63, wv = tid >> 6;
    int quad = lane >> 4, l16 = lane & 15;
    floatx4 zero = {0.f, 0.f, 0.f, 0.f};
    floatx4 acc[2][4];
#pragma unroll
    for (int mi = 0; mi < 2; mi++)
#pragma unroll
        for (int ci = 0; ci < 4; ci++) acc[mi][ci] = zero;

    for (int k0 = 0; k0 < 256; k0 += 64) {
        {
            int m = tid >> 1;
            int ob = (tid & 1) * 4;
            const float* src = x + (size_t)(m0 + m) * DIMM + k0 + ob * 8;
            short* dst = &As[m * 72 + ob * 8];
#pragma unroll
            for (int i2 = 0; i2 < 4; i2++) {
                floatx4 f0 = *(const floatx4*)(src + i2 * 8);
                floatx4 f1 = *(const floatx4*)(src + i2 * 8 + 4);
                short8 pk;
                pk[0] = (short)f2bf(f0[0]); pk[1] = (short)f2bf(f0[1]);
                pk[2] = (short)f2bf(f0[2]); pk[3] = (short)f2bf(f0[3]);
                pk[4] = (short)f2bf(f1[0]); pk[5] = (short)f2bf(f1[1]);
                pk[6] = (short)f2bf(f1[2]); pk[7] = (short)f2bf(f1[3]);
                *(short8*)(dst + i2 * 8) = pk;
            }
        }
#pragma unroll
        for (int i2 = 0; i2 < 2; i2++) {
            int idx = tid + 256 * i2;
            int c = idx >> 3, o = idx & 7;
            *(short8*)&Bs[c * 72 + o * 8] =
                *(const short8*)(const short*)(w16 + (size_t)(c0 + c) * 256 + k0 + o * 8);
        }
        __syncthreads();
#pragma unroll
        for (int kc = 0; kc < 2; kc++) {
            short8 af[2], bf[4];
#pragma unroll
            for (int mi = 0; mi < 2; mi++)
                af[mi] = *(const short8*)&As[(wv * 32 + mi * 16 + l16) * 72 + (kc * 4 + quad) * 8];
#pragma unroll
            for (int ci = 0; ci < 4; ci++)
                bf[ci] = *(const short8*)&Bs[(ci * 16 + l16) * 72 + (kc * 4 + quad) * 8];
#pragma unroll
            for (int mi = 0; mi < 2; mi++)
#pragma unroll
                for (int ci = 0; ci < 4; ci++)
                    acc[mi][ci] = __builtin_amdgcn_mfma_f32_16x16x32_bf16(
                        af[mi], bf[ci], acc[mi][ci], 0, 0, 0);
        }
        __syncthreads();
    }
#pragma unroll
    for (int mi = 0; mi < 2; mi++) {
        int mbase = m0 + wv * 32 + mi * 16 + quad * 4;
#pragma unroll
        for (int ci = 0; ci < 4; ci++) {
            int c = c0 + ci * 16 + l16;
#pragma unroll
            for (int r = 0; r < 4; r++) {
                int m = mbase + r;
                int b = m / NN, n = m - b * NN;
                float val = acc[mi][ci][r];
                size_t off = ((size_t)b * CC + c) * NN + n;
                v_nchw[off] = val;
                v16[off] = f2bf(val);
            }
        }
    }
}

// ===========================================================================
// Fused depthwise 3x3 + BN (+ pools of BN output) (+ optional gelu on out).
// One block per (b,c). Input/output NCHW fp32.
// ===========================================================================
template <bool GELU>
__global__ __launch_bounds__(256) void dwconv_pool_k(
    const float* __restrict__ in, const float* __restrict__ w,
    const float* __restrict__ g, const float* __restrict__ bparm,
    const float* __restrict__ m, const float* __restrict__ v,
    float* __restrict__ out, float* __restrict__ oavg, float* __restrict__ omax) {
    __shared__ float Us[56 * 57];
    __shared__ float Cs[NN];
    int bc = blockIdx.x;
    int c = bc & 255;
    int tid = threadIdx.x;
    const float* ip = in + (size_t)bc * NN;
    for (int i = tid; i < NN; i += 256) {
        int y = i / 56, x = i - y * 56;
        Us[y * 57 + x] = ip[i];
    }
    float w0 = w[c * 9 + 0], w1 = w[c * 9 + 1], w2 = w[c * 9 + 2];
    float w3 = w[c * 9 + 3], w4 = w[c * 9 + 4], w5 = w[c * 9 + 5];
    float w6 = w[c * 9 + 6], w7 = w[c * 9 + 7], w8 = w[c * 9 + 8];
    float s = g[c] * rsqrtf(v[c] + EPSF);
    float sh = bparm[c] - m[c] * s;
    __syncthreads();
    for (int i = tid; i < NN; i += 256) {
        int y = i / 56, x = i - y * 56;
        bool ym = y > 0, yp = y < 55, xm = x > 0, xp = x < 55;
        const float* r1 = &Us[(y - 1) * 57 + x];
        const float* r2 = &Us[y * 57 + x];
        const float* r3 = &Us[(y + 1) * 57 + x];
        float acc = r2[0] * w4;
        if (xm) acc += r2[-1] * w3;
        if (xp) acc += r2[1] * w5;
        if (ym) {
            acc += r1[0] * w1;
            if (xm) acc += r1[-1] * w0;
            if (xp) acc += r1[1] * w2;
        }
        if (yp) {
            acc += r3[0] * w7;
            if (xm) acc += r3[-1] * w6;
            if (xp) acc += r3[1] * w8;
        }
        Cs[i] = acc * s + sh;
    }
    __syncthreads();
    if (tid < 64) {
        int qy = tid >> 3, qx = tid & 7;
        const float* p0 = &Cs[(qy * 7) * 56 + qx * 7];
        float sm = 0.f, mx = -INFINITY;
#pragma unroll
        for (int py = 0; py < 7; py++)
#pragma unroll
            for (int px = 0; px < 7; px++) {
                float t = p0[py * 56 + px];
                sm += t;
                mx = fmaxf(mx, t);
            }
        oavg[(size_t)bc * 64 + tid] = sm * (1.f / 49.f);
        omax[(size_t)bc * 64 + tid] = mx;
    }
    float* op = out + (size_t)bc * NN;
    for (int i = tid; i < NN; i += 256)
        op[i] = GELU ? gelu_f(Cs[i]) : Cs[i];
}

// ===========================================================================
// conv3 as MFMA GEMM: xh16[m, co] = bf16(gelu(bn3((W@X)[co,m] + bias)))
// ===========================================================================
__global__ __launch_bounds__(256) void conv3_mfma(
    const float* __restrict__ xin, const unsigned short* __restrict__ w16,
    const float* __restrict__ bias, const float* __restrict__ g,
    const float* __restrict__ bparm, const float* __restrict__ mm,
    const float* __restrict__ vvv, unsigned short* __restrict__ out16) {
    __shared__ short As[128 * 72];
    __shared__ short Bs[64 * 72];
    int m0 = blockIdx.x * 128, c0 = blockIdx.y * 64;
    int tid = threadIdx.x;
    int lane = tid & 63, wv = tid >> 6;
    int quad = lane >> 4, l16 = lane & 15;
    int ms = tid & 127;
    int mg = m0 + ms;
    int bb = mg / NN, nn = mg - bb * NN;
    const float* arow = xin + (size_t)bb * CC * NN + nn;
    int obase = (tid >> 7) * 4;
    floatx4 zero = {0.f, 0.f, 0.f, 0.f};
    floatx4 acc[2][4];
#pragma unroll
    for (int mi = 0; mi < 2; mi++)
#pragma unroll
        for (int ci = 0; ci < 4; ci++) acc[mi][ci] = zero;

    for (int k0 = 0; k0 < 256; k0 += 64) {
#pragma unroll
        for (int ii = 0; ii < 4; ii++) {
            int o = obase + ii;
            const float* src = arow + (size_t)(k0 + o * 8) * NN;
            short8 pk;
#pragma unroll
            for (int j = 0; j < 8; j++) pk[j] = (short)f2bf(src[(size_t)j * NN]);
            *(short8*)&As[ms * 72 + o * 8] = pk;
        }
#pragma unroll
        for (int i2 = 0; i2 < 2; i2++) {
            int idx = tid + 256 * i2;
            int c = idx >> 3, o = idx & 7;
            *(short8*)&Bs[c * 72 + o * 8] =
                *(const short8*)(const short*)(w16 + (size_t)(c0 + c) * CC + k0 + o * 8);
        }
        __syncthreads();
#pragma unroll
        for (int kc = 0; kc < 2; kc++) {
            short8 af[2], bf[4];
#pragma unroll
            for (int mi = 0; mi < 2; mi++)
                af[mi] = *(const short8*)&As[(wv * 32 + mi * 16 + l16) * 72 + (kc * 4 + quad) * 8];
#pragma unroll
            for (int ci = 0; ci < 4; ci++)
                bf[ci] = *(const short8*)&Bs[(ci * 16 + l16) * 72 + (kc * 4 + quad) * 8];
#pragma unroll
            for (int mi = 0; mi < 2; mi++)
#pragma unroll
                for (int ci = 0; ci < 4; ci++)
                    acc[mi][ci] = __builtin_amdgcn_mfma_f32_16x16x32_bf16(
                        af[mi], bf[ci], acc[mi][ci], 0, 0, 0);
        }
        __syncthreads();
    }
#pragma unroll
    for (int ci = 0; ci < 4; ci++) {
        int co = c0 + ci * 16 + l16;
        float s = g[co] * rsqrtf(vvv[co] + EPSF);
        float sh = bparm[co] - mm[co] * s;
        float bi = bias[co];
#pragma unroll
        for (int mi = 0; mi < 2; mi++) {
            int mbase = m0 + wv * 32 + mi * 16 + quad * 4;
#pragma unroll
            for (int r = 0; r < 4; r++) {
                float val = gelu_f((acc[mi][ci][r] + bi) * s + sh);
                out16[(size_t)(mbase + r) * CC + co] = f2bf(val);
            }
        }
    }
}

// ---------------------------------------------------------------------------
// attn_small[b,h,i,j] (fp32, 64x64 per (b,h))
// ---------------------------------------------------------------------------
__global__ __launch_bounds__(256) void attn_qk_k(
    const float* __restrict__ q1, const float* __restrict__ q2,
    const float* __restrict__ k1, const float* __restrict__ k2,
    float* __restrict__ attn_s) {
    int b = blockIdx.x >> 3, h = blockIdx.x & 7;
    __shared__ float Qs[64][64];
    __shared__ float Ks[64][64];
    int tid = threadIdx.x;
#pragma unroll
    for (int l = 0; l < 16; l++) {
        int e = tid + 256 * l;
        int dt = e >> 6, i = e & 63;
        int d = dt & 31;
        const float* sq = (dt < 32) ? q1 : q2;
        const float* sk = (dt < 32) ? k1 : k2;
        Qs[dt][i] = sq[((size_t)b * CC + h * 32 + d) * NQ + i];
        Ks[dt][i] = sk[((size_t)b * CC + h * 32 + d) * NQ + i];
    }
    __syncthreads();
    int i = tid & 63, jg = tid >> 6;
    float acc[16] = {};
    for (int dt = 0; dt < 64; dt++) {
        float qv = Qs[dt][i];
#pragma unroll
        for (int t = 0; t < 16; t++) acc[t] += qv * Ks[dt][jg * 16 + t];
    }
    float* outp = attn_s + (((size_t)(b * 8 + h) * 64 + i) * 64) + jg * 16;
#pragma unroll
    for (int t = 0; t < 16; t++) outp[t] = acc[t];
}

// ===========================================================================
// Split-K flash-style attention PV with MFMA.
// Grid (7 splits, 64 bh). Each block: 7 chunks of 64 n. Since bilinear
// weights are convex, M_q = max_j asub[q][j] bounds every interpolated
// logit -> single pass, fixed offset, no rescaling.
// ===========================================================================
__global__ __launch_bounds__(256) void attn_pv_k(
    const float* __restrict__ attn_s, const unsigned short* __restrict__ v16,
    float* __restrict__ part_O, float* __restrict__ part_rs) {
    __shared__ float asub[64][68];
    __shared__ float Mq[64];
    __shared__ unsigned short Vs[32][72];
    __shared__ short po4[64][4];
    __shared__ float pw4[64][4];
    int s = blockIdx.x, bh = blockIdx.y;
    int b = bh >> 3, h = bh & 7;
    int tid = threadIdx.x;
    int lane = tid & 63, wv = tid >> 6;
    int quad = lane >> 4, l16 = lane & 15;
    {
        int q = tid & 63, jg = tid >> 6;
        const float* src = attn_s + ((size_t)bh * 64 + q) * 64 + jg * 16;
        float* dst = &asub[q][jg * 16];
#pragma unroll
        for (int t = 0; t < 4; t++) {
            floatx4 f = *(const floatx4*)(src + t * 4);
            f[0] *= SCALEF; f[1] *= SCALEF; f[2] *= SCALEF; f[3] *= SCALEF;
            *(floatx4*)(dst + t * 4) = f;
        }
    }
    __syncthreads();
    if (tid < 64) {
        float mx = asub[tid][0];
        for (int j = 1; j < 64; j++) mx = fmaxf(mx, asub[tid][j]);
        Mq[tid] = mx;
    }
    __syncthreads();
    int q = wv * 16 + l16;
    float Mv = Mq[q];
    floatx4 zero = {0.f, 0.f, 0.f, 0.f};
    floatx4 acc0 = zero, acc1 = zero;
    float rsum = 0.f;
    for (int cch = 0; cch < 7; cch++) {
        int n0 = (s * 7 + cch) * 64;
        {
            int d = tid >> 3, part = tid & 7;
            *(short8*)&Vs[d][part * 8] =
                *(const short8*)(const short*)(v16 +
                    ((size_t)(b * CC + h * 32 + d)) * NN + n0 + part * 8);
        }
        if (tid < 64) {
            int n = n0 + tid;
            int oy = n / WWD, ox = n - oy * WWD;
            float sy = (oy + 0.5f) * 0.14285714285714285f - 0.5f;
            float sx = (ox + 0.5f) * 0.14285714285714285f - 0.5f;
            float fy0 = floorf(sy), fx0 = floorf(sx);
            int y0 = (int)fy0, x0 = (int)fx0;
            float fy = sy - fy0, fx = sx - fx0;
            int y0c = max(y0, 0), y1c = min(y0 + 1, 7);
            int x0c = max(x0, 0), x1c = min(x0 + 1, 7);
            po4[tid][0] = (short)(y0c * 8 + x0c);
            po4[tid][1] = (short)(y0c * 8 + x1c);
            po4[tid][2] = (short)(y1c * 8 + x0c);
            po4[tid][3] = (short)(y1c * 8 + x1c);
            pw4[tid][0] = (1.f - fy) * (1.f - fx);
            pw4[tid][1] = (1.f - fy) * fx;
            pw4[tid][2] = fy * (1.f - fx);
            pw4[tid][3] = fy * fx;
        }
        __syncthreads();
#pragma unroll
        for (int kc = 0; kc < 2; kc++) {
            short8 af;
#pragma unroll
            for (int j = 0; j < 8; j++) {
                int np = kc * 32 + quad * 8 + j;
                float val = pw4[np][0] * asub[q][po4[np][0]]
                          + pw4[np][1] * asub[q][po4[np][1]]
                          + pw4[np][2] * asub[q][po4[np][2]]
                          + pw4[np][3] * asub[q][po4[np][3]];
                float p = exp2f((val - Mv) * 1.44269504f);
                rsum += p;
                af[j] = (short)f2bf(p);
            }
            short8 bf0 = *(const short8*)&Vs[l16][kc * 32 + quad * 8];
            short8 bf1 = *(const short8*)&Vs[16 + l16][kc * 32 + quad * 8];
            acc0 = __builtin_amdgcn_mfma_f32_16x16x32_bf16(af, bf0, acc0, 0, 0, 0);
            acc1 = __builtin_amdgcn_mfma_f32_16x16x32_bf16(af, bf1, acc1, 0, 0, 0);
        }
        __syncthreads();
    }
    rsum += __shfl_xor(rsum, 16, 64);
    rsum += __shfl_xor(rsum, 32, 64);
    size_t base = ((size_t)bh * 7 + s) * 64;
    if (lane < 16) part_rs[base + wv * 16 + lane] = rsum;
#pragma unroll
    for (int nt = 0; nt < 2; nt++) {
        floatx4 a = nt ? acc1 : acc0;
#pragma unroll
        for (int r = 0; r < 4; r++) {
            int qo = wv * 16 + quad * 4 + r;
            part_O[(base + qo) * 32 + nt * 16 + l16] = a[r];
        }
    }
}

__global__ __launch_bounds__(256) void attn_red_k(
    const float* __restrict__ part_O, const float* __restrict__ part_rs,
    float* __restrict__ out_s) {
    int idx = blockIdx.x * 256 + threadIdx.x;  // 64bh * 64q * 32d
    int q = idx & 63, d = (idx >> 6) & 31, bh = idx >> 11;
    float o = 0.f, rs = 0.f;
    for (int s = 0; s < 7; s++) {
        size_t base = ((size_t)bh * 7 + s) * 64;
        o += part_O[(base + q) * 32 + d];
        rs += part_rs[base + q];
    }
    int b = bh >> 3, h = bh & 7;
    out_s[((size_t)(b * CC + h * 32 + d)) * NQ + q] = o / rs;
}

// ===========================================================================
// Fused bilinear 8x8->56x56 upsample + depthwise 3x3 + vbn -> x_low bf16 NCHW
// One block per (b,c).
// ===========================================================================
__global__ __launch_bounds__(256) void upconv_k(
    const float* __restrict__ out_s, const float* __restrict__ w,
    const float* __restrict__ g, const float* __restrict__ bparm,
    const float* __restrict__ m, const float* __restrict__ v,
    unsigned short* __restrict__ xlow16) {
    __shared__ float ts[64];
    __shared__ float Us[56 * 57];
    int bc = blockIdx.x;
    int c = bc & 255;
    int tid = threadIdx.x;
    if (tid < 64) ts[tid] = out_s[(size_t)bc * 64 + tid];
    __syncthreads();
    for (int i = tid; i < NN; i += 256) {
        int y = i / 56, x = i - y * 56;
        float sy = (y + 0.5f) * 0.14285714285714285f - 0.5f;
        float sx = (x + 0.5f) * 0.14285714285714285f - 0.5f;
        float fy0 = floorf(sy), fx0 = floorf(sx);
        int y0 = (int)fy0, x0 = (int)fx0;
        float fy = sy - fy0, fx = sx - fx0;
        int y0c = max(y0, 0), y1c = min(y0 + 1, 7);
        int x0c = max(x0, 0), x1c = min(x0 + 1, 7);
        float v00 = ts[y0c * 8 + x0c], v01 = ts[y0c * 8 + x1c];
        float v10 = ts[y1c * 8 + x0c], v11 = ts[y1c * 8 + x1c];
        Us[y * 57 + x] = (1.f - fy) * ((1.f - fx) * v00 + fx * v01) +
                         fy * ((1.f - fx) * v10 + fx * v11);
    }
    float w0 = w[c * 9 + 0], w1 = w[c * 9 + 1], w2 = w[c * 9 + 2];
    float w3 = w[c * 9 + 3], w4 = w[c * 9 + 4], w5 = w[c * 9 + 5];
    float w6 = w[c * 9 + 6], w7 = w[c * 9 + 7], w8 = w[c * 9 + 8];
    float s = g[c] * rsqrtf(v[c] + EPSF);
    float sh = bparm[c] - m[c] * s;
    __syncthreads();
    unsigned short* op = xlow16 + (size_t)bc * NN;
    for (int i = tid; i < NN; i += 256) {
        int y = i / 56, x = i - y * 56;
        bool ym = y > 0, yp = y < 55, xm = x > 0, xp = x < 55;
        const float* r1 = &Us[(y - 1) * 57 + x];
        const float* r2 = &Us[y * 57 + x];
        const float* r3 = &Us[(y + 1) * 57 + x];
        float acc = r2[0] * w4;
        if (xm) acc += r2[-1] * w3;
        if (xp) acc += r2[1] * w5;
        if (ym) {
            acc += r1[0] * w1;
            if (xm) acc += r1[-1] * w0;
            if (xp) acc += r1[1] * w2;
        }
        if (yp) {
            acc += r3[0] * w7;
            if (xm) acc += r3[-1] * w6;
            if (xp) acc += r3[1] * w8;
        }
        op[i] = f2bf(acc * s + sh);
    }
}

// ===========================================================================
// Final projection MFMA: y[m, co] = sum_{k<512} cat[m,k]*W[co,k] + bias[co]
// k<256: xh16 bf16 [m][k]; k>=256: xlow16 bf16 NCHW (transpose staging).
// ===========================================================================
__global__ __launch_bounds__(256) void proj_mfma(
    const unsigned short* __restrict__ xh16, const unsigned short* __restrict__ xl16,
    const unsigned short* __restrict__ w16, const float* __restrict__ bias,
    float* __restrict__ y) {
    __shared__ short As[128 * 72];
    __shared__ short Bs[64 * 72];
    int m0 = blockIdx.x * 128, c0 = blockIdx.y * 64;
    int tid = threadIdx.x;
    int lane = tid & 63, wv = tid >> 6;
    int quad = lane >> 4, l16 = lane & 15;
    int ms = tid & 127;
    int mg = m0 + ms;
    int bb = mg / NN, nn = mg - bb * NN;
    const unsigned short* lrow = xl16 + (size_t)bb * CC * NN + nn;
    int obase = (tid >> 7) * 4;
    floatx4 zero = {0.f, 0.f, 0.f, 0.f};
    floatx4 acc[2][4];
#pragma unroll
    for (int mi = 0; mi < 2; mi++)
#pragma unroll
        for (int ci = 0; ci < 4; ci++) acc[mi][ci] = zero;

    for (int k0 = 0; k0 < 512; k0 += 64) {
        if (k0 < 256) {
#pragma unroll
            for (int i2 = 0; i2 < 4; i2++) {
                int idx = tid + 256 * i2;
                int m = idx >> 3, o = idx & 7;
                *(short8*)&As[m * 72 + o * 8] =
                    *(const short8*)(const short*)(xh16 + (size_t)(m0 + m) * CC + k0 + o * 8);
            }
        } else {
#pragma unroll
            for (int ii = 0; ii < 4; ii++) {
                int o = obase + ii;
                const unsigned short* src = lrow + (size_t)(k0 - 256 + o * 8) * NN;
                short8 pk;
#pragma unroll
                for (int j = 0; j < 8; j++) pk[j] = (short)src[(size_t)j * NN];
                *(short8*)&As[ms * 72 + o * 8] = pk;
            }
        }
#pragma unroll
        for (int i2 = 0; i2 < 2; i2++) {
            int idx = tid + 256 * i2;
            int c = idx >> 3, o = idx & 7;
            *(short8*)&Bs[c * 72 + o * 8] =
                *(const short8*)(const short*)(w16 + (size_t)(c0 + c) * DIMM + k0 + o * 8);
        }
        __syncthreads();
#pragma unroll
        for (int kc = 0; kc < 2; kc++) {
            short8 af[2], bf[4];
#pragma unroll
            for (int mi = 0; mi < 2; mi++)
                af[mi] = *(const short8*)&As[(wv * 32 + mi * 16 + l16) * 72 + (kc * 4 + quad) * 8];
#pragma unroll
            for (int ci = 0; ci < 4; ci++)
                bf[ci] = *(const short8*)&Bs[(ci * 16 + l16) * 72 + (kc * 4 + quad) * 8];
#pragma unroll
            for (int mi = 0; mi < 2; mi++)
#pragma unroll
                for (int ci = 0; ci < 4; ci++)
                    acc[mi][ci] = __builtin_amdgcn_mfma_f32_16x16x32_bf16(
                        af[mi], bf[ci], acc[mi][ci], 0, 0, 0);
        }
        __syncthreads();
    }
#pragma unroll
    for (int mi = 0; mi < 2; mi++) {
        int mbase = m0 + wv * 32 + mi * 16 + quad * 4;
#pragma unroll
        for (int ci = 0; ci < 4; ci++) {
            int co = c0 + ci * 16 + l16;
            float bi = bias[co];
#pragma unroll
            for (int r = 0; r < 4; r++)
                y[(size_t)(mbase + r) * DIMM + co] = acc[mi][ci][r] + bi;
        }
    }
}

extern "C" void kernel_launch(void* const* d_in, const int* in_sizes, int n_in,
                              void* d_out, int out_size, void* d_ws, size_t ws_size,
                              hipStream_t stream) {
    const float* x        = (const float*)d_in[0];
    const float* proj_v_w = (const float*)d_in[1];
    const float* conv1_w  = (const float*)d_in[2];
    const float* conv2_w  = (const float*)d_in[3];
    const float* conv3_w  = (const float*)d_in[4];
    const float* conv3_b  = (const float*)d_in[5];
    const float* v_conv_w = (const float*)d_in[6];
    const float* proj_w   = (const float*)d_in[7];
    const float* proj_b   = (const float*)d_in[8];
    const float* bn1_g = (const float*)d_in[9],  *bn1_b = (const float*)d_in[10];
    const float* bn1_m = (const float*)d_in[11], *bn1_v = (const float*)d_in[12];
    const float* bn2_g = (const float*)d_in[13], *bn2_b = (const float*)d_in[14];
    const float* bn2_m = (const float*)d_in[15], *bn2_v = (const float*)d_in[16];
    const float* bn3_g = (const float*)d_in[17], *bn3_b = (const float*)d_in[18];
    const float* bn3_m = (const float*)d_in[19], *bn3_v = (const float*)d_in[20];
    const float* vbn_g = (const float*)d_in[21], *vbn_b = (const float*)d_in[22];
    const float* vbn_m = (const float*)d_in[23], *vbn_v = (const float*)d_in[24];

    float* ws = (float*)d_ws;
    const size_t big = (size_t)BB * CC * NN;  // 6,422,528 floats
    float* v_nchw = ws;                 // fp32 NCHW; dead after conv1 -> xlow16 overlays
    float* bufA   = ws + big;           // gelu(bn1(conv1)) fp32 NCHW
    float* bufB   = ws + 2 * big;       // bn2(conv2) fp32 NCHW
    unsigned short* v16  = (unsigned short*)(ws + 3 * big);  // v bf16 NCHW
    unsigned short* xh16 = v16 + big;                        // x_high bf16 (B,N,C)
    float* small = ws + 4 * big;
    float* q1 = small;
    float* q2 = q1 + (size_t)BB * CC * NQ;
    float* k1 = q2 + (size_t)BB * CC * NQ;
    float* k2 = k1 + (size_t)BB * CC * NQ;
    float* attn_s = k2 + (size_t)BB * CC * NQ;               // (B,NH,64,64)
    float* out_s  = attn_s + (size_t)BB * NHEAD * NQ * NQ;   // (B,C,64)
    float* part_O = out_s + (size_t)BB * CC * NQ;            // 64*7*64*32
    float* part_rs = part_O + (size_t)64 * 7 * 64 * 32;      // 64*7*64
    unsigned short* w16v  = (unsigned short*)(part_rs + 64 * 7 * 64);
    unsigned short* w16c3 = w16v + 65536;
    unsigned short* w16p  = w16c3 + 65536;  // 262144 shorts
    unsigned short* xlow16 = (unsigned short*)ws;  // overlays v_nchw (dead)

    cast_k<<<256, 256, 0, stream>>>(proj_v_w, w16v, 65536);
    cast_k<<<256, 256, 0, stream>>>(conv3_w, w16c3, 65536);
    cast_k<<<1024, 256, 0, stream>>>(proj_w, w16p, 262144);

    gemm_v_mfma<<<dim3(196, 4), 256, 0, stream>>>(x, w16v, v_nchw, v16);
    dwconv_pool_k<true><<<BB * CC, 256, 0, stream>>>(
        v_nchw, conv1_w, bn1_g, bn1_b, bn1_m, bn1_v, bufA, q1, q2);
    dwconv_pool_k<false><<<BB * CC, 256, 0, stream>>>(
        bufA, conv2_w, bn2_g, bn2_b, bn2_m, bn2_v, bufB, k1, k2);
    conv3_mfma<<<dim3(196, 4), 256, 0, stream>>>(bufB, w16c3, conv3_b,
                                                 bn3_g, bn3_b, bn3_m, bn3_v, xh16);
    attn_qk_k<<<64, 256, 0, stream>>>(q1, q2, k1, k2, attn_s);
    attn_pv_k<<<dim3(7, 64), 256, 0, stream>>>(attn_s, v16, part_O, part_rs);
    attn_red_k<<<512, 256, 0, stream>>>(part_O, part_rs, out_s);
    upconv_k<<<BB * CC, 256, 0, stream>>>(out_s, v_conv_w,
                                          vbn_g, vbn_b, vbn_m, vbn_v, xlow16);
    proj_mfma<<<dim3(196, 8), 256, 0, stream>>>(xh16, xlow16, w16p, proj_b, (float*)d_out);
}

// Round 4
// 310.518 us; speedup vs baseline: 2.2078x; 1.0970x over previous
//
#include <hip/hip_runtime.h>
#include <math.h>

#define BB 8
#define HH 56
#define WWD 56
#define NN 3136
#define CC 256
#define DIMM 512
#define NHEAD 8
#define NQ 64
#define EPSF 1e-5f
#define SCALEF 0.04419417382415922f

typedef __attribute__((ext_vector_type(8))) short short8;
typedef __attribute__((ext_vector_type(4))) float floatx4;

__device__ __forceinline__ float gelu_f(float x) {
    return 0.5f * x * (1.f + erff(x * 0.70710678118654752f));
}
__device__ __forceinline__ unsigned short f2bf(float f) {
    union { float f; unsigned u; } v; v.f = f;
    return (unsigned short)((v.u + 0x7fffu + ((v.u >> 16) & 1u)) >> 16);
}
__device__ __forceinline__ float bf2f(unsigned short u) {
    union { unsigned u; float f; } v; v.u = ((unsigned)u) << 16;
    return v.f;
}

__global__ __launch_bounds__(256) void cast_k(const float* __restrict__ s,
                                              unsigned short* __restrict__ d, int n) {
    int i = blockIdx.x * 256 + threadIdx.x;
    if (i < n) d[i] = f2bf(s[i]);
}

// ===========================================================================
// MFMA GEMM, transposed orientation: A-side = c (weights), B-side = n (x).
// v16[b,c,n] = bf16( sum_{k<256} x[(b*NN+n)*512 + k] * w16[c*256 + k] )
// D's l16 axis = n -> NCHW stores are 32B-contiguous per quad.
// ===========================================================================
__global__ __launch_bounds__(256) void gemm_v_mfma(
    const float* __restrict__ x, const unsigned short* __restrict__ w16,
    unsigned short* __restrict__ v16) {
    __shared__ short Ws[64 * 72];    // c rows, k-contig
    __shared__ short Xs[128 * 72];   // n rows, k-contig
    int n0 = blockIdx.x * 128, c0 = blockIdx.y * 64;
    int tid = threadIdx.x;
    int lane = tid & 63, wv = tid >> 6;
    int quad = lane >> 4, l16 = lane & 15;
    floatx4 zero = {0.f, 0.f, 0.f, 0.f};
    floatx4 acc[2][4];
#pragma unroll
    for (int ni = 0; ni < 2; ni++)
#pragma unroll
        for (int ci = 0; ci < 4; ci++) acc[ni][ci] = zero;

    for (int k0 = 0; k0 < 256; k0 += 64) {
        // Xs: x fp32 k-contiguous; thread -> (m = tid>>1, 4 octets)
        {
            int m = tid >> 1;
            int ob = (tid & 1) * 4;
            const float* src = x + (size_t)(n0 + m) * DIMM + k0 + ob * 8;
            short* dst = &Xs[m * 72 + ob * 8];
#pragma unroll
            for (int i2 = 0; i2 < 4; i2++) {
                floatx4 f0 = *(const floatx4*)(src + i2 * 8);
                floatx4 f1 = *(const floatx4*)(src + i2 * 8 + 4);
                short8 pk;
                pk[0] = (short)f2bf(f0[0]); pk[1] = (short)f2bf(f0[1]);
                pk[2] = (short)f2bf(f0[2]); pk[3] = (short)f2bf(f0[3]);
                pk[4] = (short)f2bf(f1[0]); pk[5] = (short)f2bf(f1[1]);
                pk[6] = (short)f2bf(f1[2]); pk[7] = (short)f2bf(f1[3]);
                *(short8*)(dst + i2 * 8) = pk;
            }
        }
        // Ws: bf16 weights, direct 16B copies (512 octets, 256 threads x 2)
#pragma unroll
        for (int i2 = 0; i2 < 2; i2++) {
            int idx = tid + 256 * i2;
            int c = idx >> 3, o = idx & 7;
            *(short8*)&Ws[c * 72 + o * 8] =
                *(const short8*)(const short*)(w16 + (size_t)(c0 + c) * 256 + k0 + o * 8);
        }
        __syncthreads();
#pragma unroll
        for (int kc = 0; kc < 2; kc++) {
            short8 af[4], bf[2];
#pragma unroll
            for (int ci = 0; ci < 4; ci++)
                af[ci] = *(const short8*)&Ws[(ci * 16 + l16) * 72 + (kc * 4 + quad) * 8];
#pragma unroll
            for (int ni = 0; ni < 2; ni++)
                bf[ni] = *(const short8*)&Xs[(wv * 32 + ni * 16 + l16) * 72 + (kc * 4 + quad) * 8];
#pragma unroll
            for (int ni = 0; ni < 2; ni++)
#pragma unroll
                for (int ci = 0; ci < 4; ci++)
                    acc[ni][ci] = __builtin_amdgcn_mfma_f32_16x16x32_bf16(
                        af[ci], bf[ni], acc[ni][ci], 0, 0, 0);
        }
        __syncthreads();
    }
#pragma unroll
    for (int ni = 0; ni < 2; ni++) {
        int ng = n0 + wv * 32 + ni * 16 + l16;
        int b = ng / NN, n = ng - b * NN;
#pragma unroll
        for (int ci = 0; ci < 4; ci++) {
#pragma unroll
            for (int r = 0; r < 4; r++) {
                int c = c0 + ci * 16 + quad * 4 + r;
                v16[((size_t)b * CC + c) * NN + n] = f2bf(acc[ni][ci][r]);
            }
        }
    }
}

// ===========================================================================
// Fused depthwise 3x3 + BN (+ pools of BN output) (+ optional gelu on out).
// One block per (b,c). bf16 NCHW in/out; pools from fp32 pre-rounding values.
// ===========================================================================
template <bool GELU>
__global__ __launch_bounds__(256) void dwconv_pool_k(
    const unsigned short* __restrict__ in, const float* __restrict__ w,
    const float* __restrict__ g, const float* __restrict__ bparm,
    const float* __restrict__ m, const float* __restrict__ v,
    unsigned short* __restrict__ out, float* __restrict__ oavg,
    float* __restrict__ omax) {
    __shared__ float Us[56 * 57];
    __shared__ float Cs[NN];
    int bc = blockIdx.x;
    int c = bc & 255;
    int tid = threadIdx.x;
    const unsigned short* ip = in + (size_t)bc * NN;
    for (int i = tid; i < NN; i += 256) {
        int y = i / 56, x = i - y * 56;
        Us[y * 57 + x] = bf2f(ip[i]);
    }
    float w0 = w[c * 9 + 0], w1 = w[c * 9 + 1], w2 = w[c * 9 + 2];
    float w3 = w[c * 9 + 3], w4 = w[c * 9 + 4], w5 = w[c * 9 + 5];
    float w6 = w[c * 9 + 6], w7 = w[c * 9 + 7], w8 = w[c * 9 + 8];
    float s = g[c] * rsqrtf(v[c] + EPSF);
    float sh = bparm[c] - m[c] * s;
    __syncthreads();
    for (int i = tid; i < NN; i += 256) {
        int y = i / 56, x = i - y * 56;
        bool ym = y > 0, yp = y < 55, xm = x > 0, xp = x < 55;
        const float* r1 = &Us[(y - 1) * 57 + x];
        const float* r2 = &Us[y * 57 + x];
        const float* r3 = &Us[(y + 1) * 57 + x];
        float acc = r2[0] * w4;
        if (xm) acc += r2[-1] * w3;
        if (xp) acc += r2[1] * w5;
        if (ym) {
            acc += r1[0] * w1;
            if (xm) acc += r1[-1] * w0;
            if (xp) acc += r1[1] * w2;
        }
        if (yp) {
            acc += r3[0] * w7;
            if (xm) acc += r3[-1] * w6;
            if (xp) acc += r3[1] * w8;
        }
        Cs[i] = acc * s + sh;
    }
    __syncthreads();
    if (tid < 64) {
        int qy = tid >> 3, qx = tid & 7;
        const float* p0 = &Cs[(qy * 7) * 56 + qx * 7];
        float sm = 0.f, mx = -INFINITY;
#pragma unroll
        for (int py = 0; py < 7; py++)
#pragma unroll
            for (int px = 0; px < 7; px++) {
                float t = p0[py * 56 + px];
                sm += t;
                mx = fmaxf(mx, t);
            }
        oavg[(size_t)bc * 64 + tid] = sm * (1.f / 49.f);
        omax[(size_t)bc * 64 + tid] = mx;
    }
    unsigned short* op = out + (size_t)bc * NN;
    for (int i = tid; i < NN; i += 256)
        op[i] = f2bf(GELU ? gelu_f(Cs[i]) : Cs[i]);
}

// ===========================================================================
// conv3 as MFMA GEMM: xh16[m, co] = bf16(gelu(bn3((W@X)[co,m] + bias)))
// A = X (bf16 NCHW, transpose staging, plain 2B copies), B = conv3_w bf16.
// ===========================================================================
__global__ __launch_bounds__(256) void conv3_mfma(
    const unsigned short* __restrict__ xin, const unsigned short* __restrict__ w16,
    const float* __restrict__ bias, const float* __restrict__ g,
    const float* __restrict__ bparm, const float* __restrict__ mm,
    const float* __restrict__ vvv, unsigned short* __restrict__ out16) {
    __shared__ short As[128 * 72];
    __shared__ short Bs[64 * 72];
    int m0 = blockIdx.x * 128, c0 = blockIdx.y * 64;
    int tid = threadIdx.x;
    int lane = tid & 63, wv = tid >> 6;
    int quad = lane >> 4, l16 = lane & 15;
    int ms = tid & 127;
    int mg = m0 + ms;
    int bb = mg / NN, nn = mg - bb * NN;
    const unsigned short* arow = xin + (size_t)bb * CC * NN + nn;
    int obase = (tid >> 7) * 4;
    floatx4 zero = {0.f, 0.f, 0.f, 0.f};
    floatx4 acc[2][4];
#pragma unroll
    for (int mi = 0; mi < 2; mi++)
#pragma unroll
        for (int ci = 0; ci < 4; ci++) acc[mi][ci] = zero;

    for (int k0 = 0; k0 < 256; k0 += 64) {
#pragma unroll
        for (int ii = 0; ii < 4; ii++) {
            int o = obase + ii;
            const unsigned short* src = arow + (size_t)(k0 + o * 8) * NN;
            short8 pk;
#pragma unroll
            for (int j = 0; j < 8; j++) pk[j] = (short)src[(size_t)j * NN];
            *(short8*)&As[ms * 72 + o * 8] = pk;
        }
#pragma unroll
        for (int i2 = 0; i2 < 2; i2++) {
            int idx = tid + 256 * i2;
            int c = idx >> 3, o = idx & 7;
            *(short8*)&Bs[c * 72 + o * 8] =
                *(const short8*)(const short*)(w16 + (size_t)(c0 + c) * CC + k0 + o * 8);
        }
        __syncthreads();
#pragma unroll
        for (int kc = 0; kc < 2; kc++) {
            short8 af[2], bf[4];
#pragma unroll
            for (int mi = 0; mi < 2; mi++)
                af[mi] = *(const short8*)&As[(wv * 32 + mi * 16 + l16) * 72 + (kc * 4 + quad) * 8];
#pragma unroll
            for (int ci = 0; ci < 4; ci++)
                bf[ci] = *(const short8*)&Bs[(ci * 16 + l16) * 72 + (kc * 4 + quad) * 8];
#pragma unroll
            for (int mi = 0; mi < 2; mi++)
#pragma unroll
                for (int ci = 0; ci < 4; ci++)
                    acc[mi][ci] = __builtin_amdgcn_mfma_f32_16x16x32_bf16(
                        af[mi], bf[ci], acc[mi][ci], 0, 0, 0);
        }
        __syncthreads();
    }
#pragma unroll
    for (int ci = 0; ci < 4; ci++) {
        int co = c0 + ci * 16 + l16;
        float s = g[co] * rsqrtf(vvv[co] + EPSF);
        float sh = bparm[co] - mm[co] * s;
        float bi = bias[co];
#pragma unroll
        for (int mi = 0; mi < 2; mi++) {
            int mbase = m0 + wv * 32 + mi * 16 + quad * 4;
#pragma unroll
            for (int r = 0; r < 4; r++) {
                float val = gelu_f((acc[mi][ci][r] + bi) * s + sh);
                out16[(size_t)(mbase + r) * CC + co] = f2bf(val);
            }
        }
    }
}

// ---------------------------------------------------------------------------
// attn_small[b,h,i,j] (fp32, 64x64 per (b,h))
// ---------------------------------------------------------------------------
__global__ __launch_bounds__(256) void attn_qk_k(
    const float* __restrict__ q1, const float* __restrict__ q2,
    const float* __restrict__ k1, const float* __restrict__ k2,
    float* __restrict__ attn_s) {
    int b = blockIdx.x >> 3, h = blockIdx.x & 7;
    __shared__ float Qs[64][64];
    __shared__ float Ks[64][64];
    int tid = threadIdx.x;
#pragma unroll
    for (int l = 0; l < 16; l++) {
        int e = tid + 256 * l;
        int dt = e >> 6, i = e & 63;
        int d = dt & 31;
        const float* sq = (dt < 32) ? q1 : q2;
        const float* sk = (dt < 32) ? k1 : k2;
        Qs[dt][i] = sq[((size_t)b * CC + h * 32 + d) * NQ + i];
        Ks[dt][i] = sk[((size_t)b * CC + h * 32 + d) * NQ + i];
    }
    __syncthreads();
    int i = tid & 63, jg = tid >> 6;
    float acc[16] = {};
    for (int dt = 0; dt < 64; dt++) {
        float qv = Qs[dt][i];
#pragma unroll
        for (int t = 0; t < 16; t++) acc[t] += qv * Ks[dt][jg * 16 + t];
    }
    float* outp = attn_s + (((size_t)(b * 8 + h) * 64 + i) * 64) + jg * 16;
#pragma unroll
    for (int t = 0; t < 16; t++) outp[t] = acc[t];
}

// ===========================================================================
// Split-K flash-style attention PV with MFMA (convex-combination max bound).
// ===========================================================================
__global__ __launch_bounds__(256) void attn_pv_k(
    const float* __restrict__ attn_s, const unsigned short* __restrict__ v16,
    float* __restrict__ part_O, float* __restrict__ part_rs) {
    __shared__ float asub[64][68];
    __shared__ float Mq[64];
    __shared__ unsigned short Vs[32][72];
    __shared__ short po4[64][4];
    __shared__ float pw4[64][4];
    int s = blockIdx.x, bh = blockIdx.y;
    int b = bh >> 3, h = bh & 7;
    int tid = threadIdx.x;
    int lane = tid & 63, wv = tid >> 6;
    int quad = lane >> 4, l16 = lane & 15;
    {
        int q = tid & 63, jg = tid >> 6;
        const float* src = attn_s + ((size_t)bh * 64 + q) * 64 + jg * 16;
        float* dst = &asub[q][jg * 16];
#pragma unroll
        for (int t = 0; t < 4; t++) {
            floatx4 f = *(const floatx4*)(src + t * 4);
            f[0] *= SCALEF; f[1] *= SCALEF; f[2] *= SCALEF; f[3] *= SCALEF;
            *(floatx4*)(dst + t * 4) = f;
        }
    }
    __syncthreads();
    if (tid < 64) {
        float mx = asub[tid][0];
        for (int j = 1; j < 64; j++) mx = fmaxf(mx, asub[tid][j]);
        Mq[tid] = mx;
    }
    __syncthreads();
    int q = wv * 16 + l16;
    float Mv = Mq[q];
    floatx4 zero = {0.f, 0.f, 0.f, 0.f};
    floatx4 acc0 = zero, acc1 = zero;
    float rsum = 0.f;
    for (int cch = 0; cch < 7; cch++) {
        int n0 = (s * 7 + cch) * 64;
        {
            int d = tid >> 3, part = tid & 7;
            *(short8*)&Vs[d][part * 8] =
                *(const short8*)(const short*)(v16 +
                    ((size_t)(b * CC + h * 32 + d)) * NN + n0 + part * 8);
        }
        if (tid < 64) {
            int n = n0 + tid;
            int oy = n / WWD, ox = n - oy * WWD;
            float sy = (oy + 0.5f) * 0.14285714285714285f - 0.5f;
            float sx = (ox + 0.5f) * 0.14285714285714285f - 0.5f;
            float fy0 = floorf(sy), fx0 = floorf(sx);
            int y0 = (int)fy0, x0 = (int)fx0;
            float fy = sy - fy0, fx = sx - fx0;
            int y0c = max(y0, 0), y1c = min(y0 + 1, 7);
            int x0c = max(x0, 0), x1c = min(x0 + 1, 7);
            po4[tid][0] = (short)(y0c * 8 + x0c);
            po4[tid][1] = (short)(y0c * 8 + x1c);
            po4[tid][2] = (short)(y1c * 8 + x0c);
            po4[tid][3] = (short)(y1c * 8 + x1c);
            pw4[tid][0] = (1.f - fy) * (1.f - fx);
            pw4[tid][1] = (1.f - fy) * fx;
            pw4[tid][2] = fy * (1.f - fx);
            pw4[tid][3] = fy * fx;
        }
        __syncthreads();
#pragma unroll
        for (int kc = 0; kc < 2; kc++) {
            short8 af;
#pragma unroll
            for (int j = 0; j < 8; j++) {
                int np = kc * 32 + quad * 8 + j;
                float val = pw4[np][0] * asub[q][po4[np][0]]
                          + pw4[np][1] * asub[q][po4[np][1]]
                          + pw4[np][2] * asub[q][po4[np][2]]
                          + pw4[np][3] * asub[q][po4[np][3]];
                float p = exp2f((val - Mv) * 1.44269504f);
                rsum += p;
                af[j] = (short)f2bf(p);
            }
            short8 bf0 = *(const short8*)&Vs[l16][kc * 32 + quad * 8];
            short8 bf1 = *(const short8*)&Vs[16 + l16][kc * 32 + quad * 8];
            acc0 = __builtin_amdgcn_mfma_f32_16x16x32_bf16(af, bf0, acc0, 0, 0, 0);
            acc1 = __builtin_amdgcn_mfma_f32_16x16x32_bf16(af, bf1, acc1, 0, 0, 0);
        }
        __syncthreads();
    }
    rsum += __shfl_xor(rsum, 16, 64);
    rsum += __shfl_xor(rsum, 32, 64);
    size_t base = ((size_t)bh * 7 + s) * 64;
    if (lane < 16) part_rs[base + wv * 16 + lane] = rsum;
#pragma unroll
    for (int nt = 0; nt < 2; nt++) {
        floatx4 a = nt ? acc1 : acc0;
#pragma unroll
        for (int r = 0; r < 4; r++) {
            int qo = wv * 16 + quad * 4 + r;
            part_O[(base + qo) * 32 + nt * 16 + l16] = a[r];
        }
    }
}

__global__ __launch_bounds__(256) void attn_red_k(
    const float* __restrict__ part_O, const float* __restrict__ part_rs,
    float* __restrict__ out_s) {
    int idx = blockIdx.x * 256 + threadIdx.x;
    int q = idx & 63, d = (idx >> 6) & 31, bh = idx >> 11;
    float o = 0.f, rs = 0.f;
    for (int s = 0; s < 7; s++) {
        size_t base = ((size_t)bh * 7 + s) * 64;
        o += part_O[(base + q) * 32 + d];
        rs += part_rs[base + q];
    }
    int b = bh >> 3, h = bh & 7;
    out_s[((size_t)(b * CC + h * 32 + d)) * NQ + q] = o / rs;
}

// ===========================================================================
// Fused bilinear upsample + depthwise 3x3 + vbn -> x_low bf16 NCHW
// ===========================================================================
__global__ __launch_bounds__(256) void upconv_k(
    const float* __restrict__ out_s, const float* __restrict__ w,
    const float* __restrict__ g, const float* __restrict__ bparm,
    const float* __restrict__ m, const float* __restrict__ v,
    unsigned short* __restrict__ xlow16) {
    __shared__ float ts[64];
    __shared__ float Us[56 * 57];
    int bc = blockIdx.x;
    int c = bc & 255;
    int tid = threadIdx.x;
    if (tid < 64) ts[tid] = out_s[(size_t)bc * 64 + tid];
    __syncthreads();
    for (int i = tid; i < NN; i += 256) {
        int y = i / 56, x = i - y * 56;
        float sy = (y + 0.5f) * 0.14285714285714285f - 0.5f;
        float sx = (x + 0.5f) * 0.14285714285714285f - 0.5f;
        float fy0 = floorf(sy), fx0 = floorf(sx);
        int y0 = (int)fy0, x0 = (int)fx0;
        float fy = sy - fy0, fx = sx - fx0;
        int y0c = max(y0, 0), y1c = min(y0 + 1, 7);
        int x0c = max(x0, 0), x1c = min(x0 + 1, 7);
        float v00 = ts[y0c * 8 + x0c], v01 = ts[y0c * 8 + x1c];
        float v10 = ts[y1c * 8 + x0c], v11 = ts[y1c * 8 + x1c];
        Us[y * 57 + x] = (1.f - fy) * ((1.f - fx) * v00 + fx * v01) +
                         fy * ((1.f - fx) * v10 + fx * v11);
    }
    float w0 = w[c * 9 + 0], w1 = w[c * 9 + 1], w2 = w[c * 9 + 2];
    float w3 = w[c * 9 + 3], w4 = w[c * 9 + 4], w5 = w[c * 9 + 5];
    float w6 = w[c * 9 + 6], w7 = w[c * 9 + 7], w8 = w[c * 9 + 8];
    float s = g[c] * rsqrtf(v[c] + EPSF);
    float sh = bparm[c] - m[c] * s;
    __syncthreads();
    unsigned short* op = xlow16 + (size_t)bc * NN;
    for (int i = tid; i < NN; i += 256) {
        int y = i / 56, x = i - y * 56;
        bool ym = y > 0, yp = y < 55, xm = x > 0, xp = x < 55;
        const float* r1 = &Us[(y - 1) * 57 + x];
        const float* r2 = &Us[y * 57 + x];
        const float* r3 = &Us[(y + 1) * 57 + x];
        float acc = r2[0] * w4;
        if (xm) acc += r2[-1] * w3;
        if (xp) acc += r2[1] * w5;
        if (ym) {
            acc += r1[0] * w1;
            if (xm) acc += r1[-1] * w0;
            if (xp) acc += r1[1] * w2;
        }
        if (yp) {
            acc += r3[0] * w7;
            if (xm) acc += r3[-1] * w6;
            if (xp) acc += r3[1] * w8;
        }
        op[i] = f2bf(acc * s + sh);
    }
}

// ===========================================================================
// Final projection MFMA: y[m, co] = sum_{k<512} cat[m,k]*W[co,k] + bias[co]
// ===========================================================================
__global__ __launch_bounds__(256) void proj_mfma(
    const unsigned short* __restrict__ xh16, const unsigned short* __restrict__ xl16,
    const unsigned short* __restrict__ w16, const float* __restrict__ bias,
    float* __restrict__ y) {
    __shared__ short As[128 * 72];
    __shared__ short Bs[64 * 72];
    int m0 = blockIdx.x * 128, c0 = blockIdx.y * 64;
    int tid = threadIdx.x;
    int lane = tid & 63, wv = tid >> 6;
    int quad = lane >> 4, l16 = lane & 15;
    int ms = tid & 127;
    int mg = m0 + ms;
    int bb = mg / NN, nn = mg - bb * NN;
    const unsigned short* lrow = xl16 + (size_t)bb * CC * NN + nn;
    int obase = (tid >> 7) * 4;
    floatx4 zero = {0.f, 0.f, 0.f, 0.f};
    floatx4 acc[2][4];
#pragma unroll
    for (int mi = 0; mi < 2; mi++)
#pragma unroll
        for (int ci = 0; ci < 4; ci++) acc[mi][ci] = zero;

    for (int k0 = 0; k0 < 512; k0 += 64) {
        if (k0 < 256) {
#pragma unroll
            for (int i2 = 0; i2 < 4; i2++) {
                int idx = tid + 256 * i2;
                int m = idx >> 3, o = idx & 7;
                *(short8*)&As[m * 72 + o * 8] =
                    *(const short8*)(const short*)(xh16 + (size_t)(m0 + m) * CC + k0 + o * 8);
            }
        } else {
#pragma unroll
            for (int ii = 0; ii < 4; ii++) {
                int o = obase + ii;
                const unsigned short* src = lrow + (size_t)(k0 - 256 + o * 8) * NN;
                short8 pk;
#pragma unroll
                for (int j = 0; j < 8; j++) pk[j] = (short)src[(size_t)j * NN];
                *(short8*)&As[ms * 72 + o * 8] = pk;
            }
        }
#pragma unroll
        for (int i2 = 0; i2 < 2; i2++) {
            int idx = tid + 256 * i2;
            int c = idx >> 3, o = idx & 7;
            *(short8*)&Bs[c * 72 + o * 8] =
                *(const short8*)(const short*)(w16 + (size_t)(c0 + c) * DIMM + k0 + o * 8);
        }
        __syncthreads();
#pragma unroll
        for (int kc = 0; kc < 2; kc++) {
            short8 af[2], bf[4];
#pragma unroll
            for (int mi = 0; mi < 2; mi++)
                af[mi] = *(const short8*)&As[(wv * 32 + mi * 16 + l16) * 72 + (kc * 4 + quad) * 8];
#pragma unroll
            for (int ci = 0; ci < 4; ci++)
                bf[ci] = *(const short8*)&Bs[(ci * 16 + l16) * 72 + (kc * 4 + quad) * 8];
#pragma unroll
            for (int mi = 0; mi < 2; mi++)
#pragma unroll
                for (int ci = 0; ci < 4; ci++)
                    acc[mi][ci] = __builtin_amdgcn_mfma_f32_16x16x32_bf16(
                        af[mi], bf[ci], acc[mi][ci], 0, 0, 0);
        }
        __syncthreads();
    }
#pragma unroll
    for (int mi = 0; mi < 2; mi++) {
        int mbase = m0 + wv * 32 + mi * 16 + quad * 4;
#pragma unroll
        for (int ci = 0; ci < 4; ci++) {
            int co = c0 + ci * 16 + l16;
            float bi = bias[co];
#pragma unroll
            for (int r = 0; r < 4; r++)
                y[(size_t)(mbase + r) * DIMM + co] = acc[mi][ci][r] + bi;
        }
    }
}

extern "C" void kernel_launch(void* const* d_in, const int* in_sizes, int n_in,
                              void* d_out, int out_size, void* d_ws, size_t ws_size,
                              hipStream_t stream) {
    const float* x        = (const float*)d_in[0];
    const float* proj_v_w = (const float*)d_in[1];
    const float* conv1_w  = (const float*)d_in[2];
    const float* conv2_w  = (const float*)d_in[3];
    const float* conv3_w  = (const float*)d_in[4];
    const float* conv3_b  = (const float*)d_in[5];
    const float* v_conv_w = (const float*)d_in[6];
    const float* proj_w   = (const float*)d_in[7];
    const float* proj_b   = (const float*)d_in[8];
    const float* bn1_g = (const float*)d_in[9],  *bn1_b = (const float*)d_in[10];
    const float* bn1_m = (const float*)d_in[11], *bn1_v = (const float*)d_in[12];
    const float* bn2_g = (const float*)d_in[13], *bn2_b = (const float*)d_in[14];
    const float* bn2_m = (const float*)d_in[15], *bn2_v = (const float*)d_in[16];
    const float* bn3_g = (const float*)d_in[17], *bn3_b = (const float*)d_in[18];
    const float* bn3_m = (const float*)d_in[19], *bn3_v = (const float*)d_in[20];
    const float* vbn_g = (const float*)d_in[21], *vbn_b = (const float*)d_in[22];
    const float* vbn_m = (const float*)d_in[23], *vbn_v = (const float*)d_in[24];

    const size_t big = (size_t)BB * CC * NN;  // 6,422,528 elements
    unsigned short* v16    = (unsigned short*)d_ws;       // v bf16 NCHW
    unsigned short* bufA16 = v16 + big;                   // gelu(bn1) bf16 NCHW
    unsigned short* bufB16 = bufA16 + big;                // bn2 bf16 NCHW
    unsigned short* xh16   = bufB16 + big;                // x_high bf16 (B,N,C)
    unsigned short* xlow16 = xh16 + big;                  // x_low bf16 NCHW
    float* small = (float*)(xlow16 + big);
    float* q1 = small;
    float* q2 = q1 + (size_t)BB * CC * NQ;
    float* k1 = q2 + (size_t)BB * CC * NQ;
    float* k2 = k1 + (size_t)BB * CC * NQ;
    float* attn_s = k2 + (size_t)BB * CC * NQ;               // (B,NH,64,64)
    float* out_s  = attn_s + (size_t)BB * NHEAD * NQ * NQ;   // (B,C,64)
    float* part_O = out_s + (size_t)BB * CC * NQ;            // 64*7*64*32
    float* part_rs = part_O + (size_t)64 * 7 * 64 * 32;      // 64*7*64
    unsigned short* w16v  = (unsigned short*)(part_rs + 64 * 7 * 64);
    unsigned short* w16c3 = w16v + 65536;
    unsigned short* w16p  = w16c3 + 65536;  // 262144 shorts

    cast_k<<<256, 256, 0, stream>>>(proj_v_w, w16v, 65536);
    cast_k<<<256, 256, 0, stream>>>(conv3_w, w16c3, 65536);
    cast_k<<<1024, 256, 0, stream>>>(proj_w, w16p, 262144);

    gemm_v_mfma<<<dim3(196, 4), 256, 0, stream>>>(x, w16v, v16);
    dwconv_pool_k<true><<<BB * CC, 256, 0, stream>>>(
        v16, conv1_w, bn1_g, bn1_b, bn1_m, bn1_v, bufA16, q1, q2);
    dwconv_pool_k<false><<<BB * CC, 256, 0, stream>>>(
        bufA16, conv2_w, bn2_g, bn2_b, bn2_m, bn2_v, bufB16, k1, k2);
    conv3_mfma<<<dim3(196, 4), 256, 0, stream>>>(bufB16, w16c3, conv3_b,
                                                 bn3_g, bn3_b, bn3_m, bn3_v, xh16);
    attn_qk_k<<<64, 256, 0, stream>>>(q1, q2, k1, k2, attn_s);
    attn_pv_k<<<dim3(7, 64), 256, 0, stream>>>(attn_s, v16, part_O, part_rs);
    attn_red_k<<<512, 256, 0, stream>>>(part_O, part_rs, out_s);
    upconv_k<<<BB * CC, 256, 0, stream>>>(out_s, v_conv_w,
                                          vbn_g, vbn_b, vbn_m, vbn_v, xlow16);
    proj_mfma<<<dim3(196, 8), 256, 0, stream>>>(xh16, xlow16, w16p, proj_b, (float*)d_out);
}